// Round 12
// baseline (646.613 us; speedup 1.0000x reference)
//
#include <hip/hip_runtime.h>
#include <hip/hip_bf16.h>
#include <stdint.h>

typedef __attribute__((ext_vector_type(8))) short bf16x8;
typedef __attribute__((ext_vector_type(4))) float f32x4;
typedef unsigned short u16;

#define M_ROWS 16384
#define N_COLS 4096
#define K_DIM  2048
#define TOPK   16
#define KSEL   16
#define CAP    48
#define INV_T  5.0f
#define DELTA  0.05f

#define BM 256
#define BN 128
#define BK 32
#define NKT (K_DIM / BK)   // 64

// ---- async global->LDS 16B copy -------------------------------------------
__device__ __forceinline__ void async_cp16(const void* g, void* l) {
  __builtin_amdgcn_global_load_lds((const __attribute__((address_space(1))) uint32_t*)g,
                                   (__attribute__((address_space(3))) uint32_t*)l,
                                   16, 0, 0);
}

__device__ __forceinline__ u16 f2bf(float f) {
  __hip_bfloat16 h = __float2bfloat16(f);   // round-to-nearest-even
  return *reinterpret_cast<u16*>(&h);
}
__device__ __forceinline__ float bf2f(u16 u) {
  return __uint_as_float(((uint32_t)u) << 16);
}
__device__ __forceinline__ uint2 pack4(float4 v) {
  uint2 r;
  r.x = (uint32_t)f2bf(v.x) | ((uint32_t)f2bf(v.y) << 16);
  r.y = (uint32_t)f2bf(v.z) | ((uint32_t)f2bf(v.w) << 16);
  return r;
}

// ---- prep: per-row inv-norm of x + bf16 cast (unnormalized) ---------------
__global__ __launch_bounds__(256) void prep_x_kernel(
    const float* __restrict__ x, u16* __restrict__ xh, float* __restrict__ invn) {
  const int row = blockIdx.x;
  const int t = threadIdx.x;
  const float4* xr = reinterpret_cast<const float4*>(x + (size_t)row * K_DIM);
  float4 v0 = xr[t];
  float4 v1 = xr[256 + t];
  float s = v0.x*v0.x + v0.y*v0.y + v0.z*v0.z + v0.w*v0.w
          + v1.x*v1.x + v1.y*v1.y + v1.z*v1.z + v1.w*v1.w;
  #pragma unroll
  for (int off = 1; off < 64; off <<= 1) s += __shfl_xor(s, off);
  __shared__ float ws4[4];
  if ((t & 63) == 0) ws4[t >> 6] = s;
  __syncthreads();
  if (t == 0) {
    float tot = ws4[0] + ws4[1] + ws4[2] + ws4[3];
    invn[row] = 1.0f / fmaxf(sqrtf(tot), 1e-12f);
  }
  uint2* xo = reinterpret_cast<uint2*>(xh + (size_t)row * K_DIM);
  xo[t] = pack4(v0);
  xo[256 + t] = pack4(v1);
}

// ---- prep: protos fp32 -> bf16 --------------------------------------------
__global__ __launch_bounds__(256) void prep_p_kernel(
    const float* __restrict__ p, u16* __restrict__ ph) {
  const int row = blockIdx.x;
  const int t = threadIdx.x;
  const float4* pr = reinterpret_cast<const float4*>(p + (size_t)row * K_DIM);
  uint2* po = reinterpret_cast<uint2*>(ph + (size_t)row * K_DIM);
  po[t] = pack4(pr[t]);
  po[256 + t] = pack4(pr[256 + t]);
}

// ---- bf16 GEMM 256x128, wave-tile 128x64, BK=32, counted vmcnt (R8 sched) -
// Geometry change only; K-loop schedule frozen from R8/R10. Per K-tile t:
// vmcnt(6)[t landed, t+1 in flight] -> barrier -> ds_read 12 frags ->
// lgkmcnt(0) -> barrier(WAR seal) -> STAGE(t+2) -> 32 MFMA.
// K-accumulation strictly ascending 32-steps -> sims bit-identical to R11.
// LDS rows are 64B; 16B-chunk swizzle c ^= (r>>1)&3 (2-way-free reads).
__global__ __launch_bounds__(256) void gemm_bf16_kernel(
    const u16* __restrict__ A, const u16* __restrict__ B, u16* __restrict__ C) {
  __shared__ __align__(16) u16 sA[2][BM * BK];   // 2 x 16 KB
  __shared__ __align__(16) u16 sB[2][BN * BK];   // 2 x 8 KB
  const int t = threadIdx.x;
  const int lane = t & 63;
  const int wid = t >> 6;
  const int wm = wid >> 1, wn = wid & 1;
  const int tm0 = blockIdx.y * BM;
  const int tn0 = blockIdx.x * BN;
  const int lr = lane & 15;
  const int hi = lane >> 4;

  f32x4 acc[8][4];
  #pragma unroll
  for (int i = 0; i < 8; ++i)
    #pragma unroll
    for (int j = 0; j < 4; ++j)
      acc[i][j] = (f32x4){0.f, 0.f, 0.f, 0.f};

  // staging: A = 1024 16B-chunks (4/thread), B = 512 (2/thread)
  // chunk ci -> row r = ci>>2, slot c = ci&3 holds global k-chunk c^((r>>1)&3)
  int aoff[4], boff[2];
  #pragma unroll
  for (int c = 0; c < 4; ++c) {
    int ci = c * 256 + t;
    int r = ci >> 2;
    aoff[c] = r * (K_DIM * 2) + (((ci & 3) ^ ((r >> 1) & 3)) << 4);
  }
  #pragma unroll
  for (int c = 0; c < 2; ++c) {
    int ci = c * 256 + t;
    int r = ci >> 2;
    boff[c] = r * (K_DIM * 2) + (((ci & 3) ^ ((r >> 1) & 3)) << 4);
  }
  const char* Abase = (const char*)(A + (size_t)tm0 * K_DIM);
  const char* Bbase = (const char*)(B + (size_t)tn0 * K_DIM);

#define STAGE(slot, kt_) do {                                                 \
    const int kb_ = (kt_) * (BK * 2);                                         \
    _Pragma("unroll")                                                         \
    for (int c = 0; c < 4; ++c)                                               \
      async_cp16(Abase + aoff[c] + kb_,                                       \
                 (char*)sA[slot] + (c * 256 + t) * 16);                       \
    _Pragma("unroll")                                                         \
    for (int c = 0; c < 2; ++c)                                               \
      async_cp16(Bbase + boff[c] + kb_,                                       \
                 (char*)sB[slot] + (c * 256 + t) * 16);                       \
  } while (0)

  STAGE(0, 0);
  STAGE(1, 1);

  for (int kt = 0; kt < NKT; ++kt) {
    // head wait: own tile-kt loads landed; tile kt+1's stay in flight
    if (kt + 1 < NKT) asm volatile("s_waitcnt vmcnt(6)" ::: "memory");
    else              asm volatile("s_waitcnt vmcnt(0)" ::: "memory");
    __builtin_amdgcn_sched_barrier(0);
    __builtin_amdgcn_s_barrier();      // all waves: tile kt ready
    asm volatile("" ::: "memory");

    const char* cA = (const char*)sA[kt & 1];
    const char* cB = (const char*)sB[kt & 1];
    bf16x8 af[8], bq[4];
    #pragma unroll
    for (int f = 0; f < 8; ++f) {
      int rA = wm * 128 + f * 16 + lr;
      af[f] = *reinterpret_cast<const bf16x8*>(
          cA + rA * 64 + ((hi ^ ((rA >> 1) & 3)) << 4));
    }
    #pragma unroll
    for (int f = 0; f < 4; ++f) {
      int rB = wn * 64 + f * 16 + lr;
      bq[f] = *reinterpret_cast<const bf16x8*>(
          cB + rB * 64 + ((hi ^ ((rB >> 1) & 3)) << 4));
    }
    asm volatile("s_waitcnt lgkmcnt(0)" ::: "memory");   // frags in regs
    __builtin_amdgcn_sched_barrier(0);
    if (kt + 2 < NKT) {
      __builtin_amdgcn_s_barrier();    // WAR seal: all waves done reading buf
      asm volatile("" ::: "memory");
      __builtin_amdgcn_sched_barrier(0);
      STAGE(kt & 1, kt + 2);           // overwrite vacated buffer
    }
    __builtin_amdgcn_s_setprio(1);
    #pragma unroll
    for (int i = 0; i < 8; ++i)
      #pragma unroll
      for (int j = 0; j < 4; ++j)
        acc[i][j] = __builtin_amdgcn_mfma_f32_16x16x32_bf16(
            af[i], bq[j], acc[i][j], 0, 0, 0);
    __builtin_amdgcn_s_setprio(0);
  }
#undef STAGE

  // C write (bf16): col = lane&15, row = (lane>>4)*4 + reg
  #pragma unroll
  for (int i = 0; i < 8; ++i) {
    #pragma unroll
    for (int j = 0; j < 4; ++j) {
      int colg = tn0 + wn * 64 + j * 16 + lr;
      int rowb = tm0 + wm * 128 + i * 16 + (hi << 2);
      #pragma unroll
      for (int r = 0; r < 4; ++r) {
        __builtin_nontemporal_store(f2bf(acc[i][j][r]),
                                    &C[(size_t)(rowb + r) * N_COLS + colg]);
      }
    }
  }
}

// ---- per-row: 2-pass radix (exact 16-bit keys) -> window rescore -> top-16
// (frozen verbatim from R11)
__global__ __launch_bounds__(256) void topk_kernel(
    const float* __restrict__ x, const float* __restrict__ protos,
    const float* __restrict__ invn, const u16* __restrict__ sims,
    int* __restrict__ sposg, float* __restrict__ svalg) {
  const int row = blockIdx.x;
  const int t = threadIdx.x;
  const int lane = t & 63;
  const int wid = t >> 6;

  __shared__ __align__(16) f32x4 lx[512];       // x row, 8 KB
  __shared__ int hist[4][257];                  // padded -> distinct banks
  __shared__ int selInfo[2];
  __shared__ int   wtotC[4], wtotW[4];
  __shared__ int   cposC[16];
  __shared__ float cargC[16];
  __shared__ int   wpos[CAP];
  __shared__ float cexact[CAP];
  __shared__ int   spos[TOPK];
  __shared__ float sval[TOPK];

  // load approx sims (bf16, nt) -> floats + exact 16-bit order keys
  const bf16x8* orow8 = reinterpret_cast<const bf16x8*>(sims + (size_t)row * N_COLS);
  float fv[16];
  uint32_t key[16];
  #pragma unroll
  for (int i = 0; i < 2; ++i) {
    bf16x8 v = __builtin_nontemporal_load(orow8 + i * 256 + t);
    #pragma unroll
    for (int c = 0; c < 8; ++c) {
      u16 u = (u16)v[c];
      fv[i * 8 + c] = bf2f(u);
      key[i * 8 + c] = (u & 0x8000) ? (uint32_t)(~u & 0xFFFF)
                                    : (uint32_t)(u | 0x8000);
    }
  }

  // stage x row into LDS (nt, streaming)
  const f32x4* xr = reinterpret_cast<const f32x4*>(x + (size_t)row * K_DIM);
  lx[t] = __builtin_nontemporal_load(xr + t);
  lx[256 + t] = __builtin_nontemporal_load(xr + 256 + t);

  // --- 2-pass radix select: exact KSEL-th largest 16-bit key ---
  uint32_t T = 0;
  int K_rem = KSEL;
  #pragma unroll
  for (int pass = 0; pass < 2; ++pass) {
    const int shift = 8 - pass * 8;
    hist[0][t] = 0; hist[1][t] = 0; hist[2][t] = 0; hist[3][t] = 0;
    __syncthreads();
    #pragma unroll
    for (int j = 0; j < 16; ++j) {
      bool ok = (pass == 0) || ((key[j] >> 8) == T);
      if (ok) atomicAdd(&hist[wid][(key[j] >> shift) & 255], 1);
    }
    __syncthreads();
    if (wid == 0) {
      const int b0 = lane << 2;
      int h0 = hist[0][b0]     + hist[1][b0]     + hist[2][b0]     + hist[3][b0];
      int h1 = hist[0][b0 + 1] + hist[1][b0 + 1] + hist[2][b0 + 1] + hist[3][b0 + 1];
      int h2 = hist[0][b0 + 2] + hist[1][b0 + 2] + hist[2][b0 + 2] + hist[3][b0 + 2];
      int h3 = hist[0][b0 + 3] + hist[1][b0 + 3] + hist[2][b0 + 3] + hist[3][b0 + 3];
      int loc = h0 + h1 + h2 + h3;
      int s = loc;
      #pragma unroll
      for (int off = 1; off < 64; off <<= 1) {
        int o = __shfl_down(s, off);
        if (lane + off < 64) s += o;
      }
      const int tail = s - loc;
      int s3 = tail + h3;
      int s2 = s3 + h2;
      int s1 = s2 + h1;
      int s0 = s1 + h0;
      int ge[4] = {s0, s1, s2, s3};
      int hh[4] = {h0, h1, h2, h3};
      #pragma unroll
      for (int k = 0; k < 4; ++k) {
        int gt = ge[k] - hh[k];
        if (gt < K_rem && ge[k] >= K_rem) {
          selInfo[0] = b0 + k;
          selInfo[1] = K_rem - gt;
        }
      }
    }
    __syncthreads();
    T = (T << 8) | (uint32_t)selInfo[0];
    K_rem = selInfo[1];
  }
  // invert key map: exact 16th-largest stored value
  const u16 ub = (T & 0x8000) ? (u16)(T ^ 0x8000) : (u16)(~T & 0xFFFF);
  const float a16 = bf2f(ub);
  const float vhi = a16 + DELTA;
  const float vlo = a16 - DELTA;
  const float inv = invn[row];

  // --- deterministic scan-based compaction: certain-ins & window ---
  int lcC = 0, lcW = 0;
  #pragma unroll
  for (int j = 0; j < 16; ++j) {
    float v = fv[j];
    if (v > vhi) ++lcC;
    else if (v >= vlo) ++lcW;
  }
  int pC = lcC, pW = lcW;
  #pragma unroll
  for (int off = 1; off < 64; off <<= 1) {
    int oC = __shfl_up(pC, off);
    int oW = __shfl_up(pW, off);
    if (lane >= off) { pC += oC; pW += oW; }
  }
  if (lane == 63) { wtotC[wid] = pC; wtotW[wid] = pW; }
  __syncthreads();
  int baseC = pC - lcC, baseW = pW - lcW;
  for (int w2 = 0; w2 < wid; ++w2) { baseC += wtotC[w2]; baseW += wtotW[w2]; }
  const int m  = wtotC[0] + wtotC[1] + wtotC[2] + wtotC[3];       // <= 15
  const int wc = min(wtotW[0] + wtotW[1] + wtotW[2] + wtotW[3], CAP);
  #pragma unroll
  for (int j = 0; j < 16; ++j) {
    float v = fv[j];
    int pos = (j >> 3) * 2048 + t * 8 + (j & 7);   // column index
    if (v > vhi) { cposC[baseC] = pos; cargC[baseC] = v; ++baseC; }
    else if (v >= vlo) { if (baseW < CAP) { wpos[baseW] = pos; ++baseW; } }
  }
  __syncthreads();

  // --- exact fp32 rescore of WINDOW members only (proven R7 path) ---
  for (int ci = wid; ci < wc; ci += 4) {
    int pidx = wpos[ci];
    const f32x4* pr = reinterpret_cast<const f32x4*>(protos + (size_t)pidx * K_DIM);
    float s = 0.f;
    #pragma unroll
    for (int i = 0; i < 8; ++i) {
      f32x4 pv = pr[i * 64 + lane];
      f32x4 xv = lx[i * 64 + lane];
      s = fmaf(pv.x, xv.x, s);
      s = fmaf(pv.y, xv.y, s);
      s = fmaf(pv.z, xv.z, s);
      s = fmaf(pv.w, xv.w, s);
    }
    #pragma unroll
    for (int off = 1; off < 64; off <<= 1) s += __shfl_xor(s, off);
    if (lane == 0) cexact[ci] = s * inv;
  }
  __syncthreads();

  // --- wave 0: pick top-(16-m) of window, merge, softmax over 16 ---
  if (wid == 0) {
    const int w_need = TOPK - m;   // >= 1 since m <= 15
    float v = (lane < wc) ? cexact[lane] : -3.0e38f;
    int pos = (lane < wc) ? wpos[lane] : 0x7fffffff;
    int rank = 0;
    for (int j = 0; j < wc; ++j) {
      float vj = __shfl(v, j);
      int   pj = __shfl(pos, j);
      if (lane < wc && j != lane)
        if (vj > v || (vj == v && pj < pos)) rank++;
    }
    bool sel = (lane < wc) && (rank < w_need);
    unsigned long long bal = __ballot(sel);
    int slot = __popcll(bal & ((1ull << lane) - 1ull));
    if (sel) { spos[m + slot] = pos; sval[m + slot] = v; }
    if (lane < m) { spos[lane] = cposC[lane]; sval[lane] = cargC[lane] * inv; }
    float av = (lane < TOPK) ? sval[lane] : -3.0e38f;
    float vm = av;
    #pragma unroll
    for (int off = 1; off < 16; off <<= 1) vm = fmaxf(vm, __shfl_xor(vm, off));
    float e = (lane < TOPK) ? expf((av - vm) * INV_T) : 0.f;
    float se = e;
    #pragma unroll
    for (int off = 1; off < 16; off <<= 1) se += __shfl_xor(se, off);
    if (lane < TOPK) {
      sposg[(size_t)row * TOPK + lane] = spos[lane];
      svalg[(size_t)row * TOPK + lane] = e / se;
    }
  }
}

// ---- pure-streaming output writer: zeros + 16 scattered values per row ----
__global__ __launch_bounds__(256) void writer_kernel(
    const int* __restrict__ sposg, const float* __restrict__ svalg,
    float* __restrict__ out) {
  const int row = blockIdx.x;
  const int t = threadIdx.x;
  __shared__ int sp[TOPK];
  __shared__ float svv[TOPK];
  if (t < TOPK) {
    sp[t] = sposg[(size_t)row * TOPK + t];
    svv[t] = svalg[(size_t)row * TOPK + t];
  }
  __syncthreads();
  f32x4* orow4w = reinterpret_cast<f32x4*>(out + (size_t)row * N_COLS);
  #pragma unroll
  for (int i = 0; i < 4; ++i) {
    f32x4 o = (f32x4){0.f, 0.f, 0.f, 0.f};
    #pragma unroll
    for (int s = 0; s < TOPK; ++s) {
      int p = sp[s];
      if ((p >> 10) == i && ((p >> 2) & 255) == t) o[p & 3] = svv[s];
    }
    __builtin_nontemporal_store(o, orow4w + i * 256 + t);
  }
}

extern "C" void kernel_launch(void* const* d_in, const int* in_sizes, int n_in,
                              void* d_out, int out_size, void* d_ws, size_t ws_size,
                              hipStream_t stream) {
  const float* x = (const float*)d_in[0];
  const float* protos = (const float*)d_in[1];
  float* out = (float*)d_out;

  char* ws = (char*)d_ws;
  u16* xh = (u16*)ws;                                        // 64 MB
  u16* ph = (u16*)(ws + (size_t)M_ROWS * K_DIM * 2);         // 16 MB (dead after gemm)
  float* invn = (float*)(ws + (size_t)(M_ROWS + N_COLS) * K_DIM * 2); // 64 KB
  // pair buffers alias the ph region — safe: topk runs after gemm completes
  int*   sposg = (int*)(ws + (size_t)M_ROWS * K_DIM * 2);               // 1 MB
  float* svalg = (float*)(ws + (size_t)M_ROWS * K_DIM * 2 + (size_t)M_ROWS * TOPK * 4); // 1 MB

  // bf16 sims live in the first half of d_out; writer overwrites all of
  // d_out with the final fp32 zeros+values AFTER topk has consumed them.
  u16* simsbf = (u16*)d_out;   // 134 MB of the 268 MB output buffer

  prep_x_kernel<<<M_ROWS, 256, 0, stream>>>(x, xh, invn);
  prep_p_kernel<<<N_COLS, 256, 0, stream>>>(protos, ph);

  dim3 gg(N_COLS / BN, M_ROWS / BM);   // (32, 64)
  gemm_bf16_kernel<<<gg, 256, 0, stream>>>(xh, ph, simsbf);

  topk_kernel<<<M_ROWS, 256, 0, stream>>>(x, protos, invn, simsbf, sposg, svalg);
  writer_kernel<<<M_ROWS, 256, 0, stream>>>(sposg, svalg, out);
}

// Round 13
// 534.574 us; speedup vs baseline: 1.2096x; 1.2096x over previous
//
#include <hip/hip_runtime.h>
#include <hip/hip_bf16.h>
#include <stdint.h>

typedef __attribute__((ext_vector_type(8))) short bf16x8;
typedef __attribute__((ext_vector_type(4))) float f32x4;
typedef unsigned short u16;

#define M_ROWS 16384
#define N_COLS 4096
#define K_DIM  2048
#define TOPK   16
#define KSEL   16
#define CAP    48
#define INV_T  5.0f
#define DELTA  0.035f

#define BM 128
#define BN 128
#define BK 64
#define NKT (K_DIM / BK)   // 32

// ---- async global->LDS 16B copy -------------------------------------------
__device__ __forceinline__ void async_cp16(const void* g, void* l) {
  __builtin_amdgcn_global_load_lds((const __attribute__((address_space(1))) uint32_t*)g,
                                   (__attribute__((address_space(3))) uint32_t*)l,
                                   16, 0, 0);
}

__device__ __forceinline__ u16 f2bf(float f) {
  __hip_bfloat16 h = __float2bfloat16(f);   // round-to-nearest-even
  return *reinterpret_cast<u16*>(&h);
}
__device__ __forceinline__ float bf2f(u16 u) {
  return __uint_as_float(((uint32_t)u) << 16);
}
__device__ __forceinline__ uint2 pack4(float4 v) {
  uint2 r;
  r.x = (uint32_t)f2bf(v.x) | ((uint32_t)f2bf(v.y) << 16);
  r.y = (uint32_t)f2bf(v.z) | ((uint32_t)f2bf(v.w) << 16);
  return r;
}

// ---- prep: per-row inv-norm of x + bf16 cast (unnormalized) ---------------
__global__ __launch_bounds__(256) void prep_x_kernel(
    const float* __restrict__ x, u16* __restrict__ xh, float* __restrict__ invn) {
  const int row = blockIdx.x;
  const int t = threadIdx.x;
  const float4* xr = reinterpret_cast<const float4*>(x + (size_t)row * K_DIM);
  float4 v0 = xr[t];
  float4 v1 = xr[256 + t];
  float s = v0.x*v0.x + v0.y*v0.y + v0.z*v0.z + v0.w*v0.w
          + v1.x*v1.x + v1.y*v1.y + v1.z*v1.z + v1.w*v1.w;
  #pragma unroll
  for (int off = 1; off < 64; off <<= 1) s += __shfl_xor(s, off);
  __shared__ float ws4[4];
  if ((t & 63) == 0) ws4[t >> 6] = s;
  __syncthreads();
  if (t == 0) {
    float tot = ws4[0] + ws4[1] + ws4[2] + ws4[3];
    invn[row] = 1.0f / fmaxf(sqrtf(tot), 1e-12f);
  }
  uint2* xo = reinterpret_cast<uint2*>(xh + (size_t)row * K_DIM);
  xo[t] = pack4(v0);
  xo[256 + t] = pack4(v1);
}

// ---- prep: protos fp32 -> bf16 --------------------------------------------
__global__ __launch_bounds__(256) void prep_p_kernel(
    const float* __restrict__ p, u16* __restrict__ ph) {
  const int row = blockIdx.x;
  const int t = threadIdx.x;
  const float4* pr = reinterpret_cast<const float4*>(p + (size_t)row * K_DIM);
  uint2* po = reinterpret_cast<uint2*>(ph + (size_t)row * K_DIM);
  po[t] = pack4(pr[t]);
  po[256 + t] = pack4(pr[256 + t]);
}

// ---- bf16 GEMM 128x128, dbuf LDS, reg-prefetch, counted vmcnt -------------
// K-loop FROZEN from R11 (proven 268us/1026TF). New: XCD-chunked 1D grid
// swizzle (order-only; sims bit-identical): each XCD owns 16 consecutive
// A-panels (512KB each) so A+B tile reads serve from its L2 (~200cy) instead
// of L3 (~600-900cy), shrinking the per-iteration head-wait stall.
__global__ __launch_bounds__(256) void gemm_bf16_kernel(
    const u16* __restrict__ A, const u16* __restrict__ B, u16* __restrict__ C) {
  __shared__ __align__(16) u16 sA[2][BM * BK];   // 2 x 16 KB
  __shared__ __align__(16) u16 sB[2][BN * BK];   // 2 x 16 KB
  const int t = threadIdx.x;
  const int lane = t & 63;
  const int wid = t >> 6;
  const int wm = wid >> 1, wn = wid & 1;
  // XCD swizzle: bid%8 = XCD (round-robin dispatch). XCD x covers
  // swz in [x*512,(x+1)*512): 16 row-panels (by), each with its 32 bx blocks
  // consecutive -> A-panel L2-resident, B streamed once per panel group.
  const int bid = blockIdx.x;
  const int swz = (bid & 7) * 512 + (bid >> 3);
  const int tm0 = (swz >> 5) * BM;      // by in [0,128)
  const int tn0 = (swz & 31) * BN;      // bx in [0,32)
  const int lr = lane & 15;
  const int hi = lane >> 4;

  f32x4 acc[4][4];
  #pragma unroll
  for (int i = 0; i < 4; ++i)
    #pragma unroll
    for (int j = 0; j < 4; ++j)
      acc[i][j] = (f32x4){0.f, 0.f, 0.f, 0.f};

  int srow[4], soff[4];
  #pragma unroll
  for (int i = 0; i < 4; ++i) {
    int c = i * 256 + t;
    int r = c >> 3;
    int ib = (c & 7) << 4;
    srow[i] = r;
    soff[i] = ib ^ ((r & 7) << 4);
  }
  const char* Abase = (const char*)(A + (size_t)tm0 * K_DIM);
  const char* Bbase = (const char*)(B + (size_t)tn0 * K_DIM);

#define STAGE(slot, kt_) do {                                                 \
    const int kb_ = (kt_) * (BK * 2);                                         \
    _Pragma("unroll")                                                         \
    for (int i = 0; i < 4; ++i) {                                             \
      async_cp16(Abase + (size_t)srow[i] * (K_DIM * 2) + kb_ + soff[i],       \
                 (char*)sA[slot] + (i * 256 + t) * 16);                       \
      async_cp16(Bbase + (size_t)srow[i] * (K_DIM * 2) + kb_ + soff[i],       \
                 (char*)sB[slot] + (i * 256 + t) * 16);                       \
    }                                                                         \
  } while (0)

  STAGE(0, 0);
  STAGE(1, 1);

  for (int kt = 0; kt < NKT; ++kt) {
    // head wait: own tile-kt loads landed; tile kt+1's stay in flight
    if (kt + 1 < NKT) asm volatile("s_waitcnt vmcnt(8)" ::: "memory");
    else              asm volatile("s_waitcnt vmcnt(0)" ::: "memory");
    __builtin_amdgcn_sched_barrier(0);
    __builtin_amdgcn_s_barrier();      // all waves: tile kt ready
    asm volatile("" ::: "memory");

    const char* cA = (const char*)sA[kt & 1];
    const char* cB = (const char*)sB[kt & 1];
    bf16x8 af[4][2], bq[4][2];
    #pragma unroll
    for (int f = 0; f < 4; ++f) {
      #pragma unroll
      for (int kk = 0; kk < 2; ++kk) {
        int rowA = wm * 64 + f * 16 + lr;
        int inbA = (kk * 64 + (hi << 4)) ^ ((rowA & 7) << 4);
        af[f][kk] = *reinterpret_cast<const bf16x8*>(cA + rowA * 128 + inbA);
        int rowB = wn * 64 + f * 16 + lr;
        int inbB = (kk * 64 + (hi << 4)) ^ ((rowB & 7) << 4);
        bq[f][kk] = *reinterpret_cast<const bf16x8*>(cB + rowB * 128 + inbB);
      }
    }
    asm volatile("s_waitcnt lgkmcnt(0)" ::: "memory");   // frags in regs
    __builtin_amdgcn_sched_barrier(0);
    if (kt + 2 < NKT) {
      __builtin_amdgcn_s_barrier();    // WAR seal: all waves done reading buf
      asm volatile("" ::: "memory");
      __builtin_amdgcn_sched_barrier(0);
      STAGE(kt & 1, kt + 2);           // overwrite vacated buffer
    }
    __builtin_amdgcn_s_setprio(1);
    #pragma unroll
    for (int kk = 0; kk < 2; ++kk)
      #pragma unroll
      for (int i = 0; i < 4; ++i)
        #pragma unroll
        for (int j = 0; j < 4; ++j)
          acc[i][j] = __builtin_amdgcn_mfma_f32_16x16x32_bf16(
              af[i][kk], bq[j][kk], acc[i][j], 0, 0, 0);
    __builtin_amdgcn_s_setprio(0);
  }
#undef STAGE

  // C write (bf16): col = lane&15, row = (lane>>4)*4 + reg
  #pragma unroll
  for (int i = 0; i < 4; ++i) {
    #pragma unroll
    for (int j = 0; j < 4; ++j) {
      int colg = tn0 + wn * 64 + j * 16 + lr;
      int rowb = tm0 + wm * 64 + i * 16 + (hi << 2);
      #pragma unroll
      for (int r = 0; r < 4; ++r) {
        __builtin_nontemporal_store(f2bf(acc[i][j][r]),
                                    &C[(size_t)(rowb + r) * N_COLS + colg]);
      }
    }
  }
}

// ---- per-row: 2-pass radix (exact 16-bit keys) -> window rescore -> top-16
// Frozen from R11 except DELTA 0.05 -> 0.035 (window ~13 -> ~9 candidates;
// boundary-miss budget 7 sigma, P ~ 6e-7 across all rows).
__global__ __launch_bounds__(256) void topk_kernel(
    const float* __restrict__ x, const float* __restrict__ protos,
    const float* __restrict__ invn, const u16* __restrict__ sims,
    int* __restrict__ sposg, float* __restrict__ svalg) {
  const int row = blockIdx.x;
  const int t = threadIdx.x;
  const int lane = t & 63;
  const int wid = t >> 6;

  __shared__ __align__(16) f32x4 lx[512];       // x row, 8 KB
  __shared__ int hist[4][257];                  // padded -> distinct banks
  __shared__ int selInfo[2];
  __shared__ int   wtotC[4], wtotW[4];
  __shared__ int   cposC[16];
  __shared__ float cargC[16];
  __shared__ int   wpos[CAP];
  __shared__ float cexact[CAP];
  __shared__ int   spos[TOPK];
  __shared__ float sval[TOPK];

  // load approx sims (bf16, nt) -> floats + exact 16-bit order keys
  const bf16x8* orow8 = reinterpret_cast<const bf16x8*>(sims + (size_t)row * N_COLS);
  float fv[16];
  uint32_t key[16];
  #pragma unroll
  for (int i = 0; i < 2; ++i) {
    bf16x8 v = __builtin_nontemporal_load(orow8 + i * 256 + t);
    #pragma unroll
    for (int c = 0; c < 8; ++c) {
      u16 u = (u16)v[c];
      fv[i * 8 + c] = bf2f(u);
      key[i * 8 + c] = (u & 0x8000) ? (uint32_t)(~u & 0xFFFF)
                                    : (uint32_t)(u | 0x8000);
    }
  }

  // stage x row into LDS (nt, streaming)
  const f32x4* xr = reinterpret_cast<const f32x4*>(x + (size_t)row * K_DIM);
  lx[t] = __builtin_nontemporal_load(xr + t);
  lx[256 + t] = __builtin_nontemporal_load(xr + 256 + t);

  // --- 2-pass radix select: exact KSEL-th largest 16-bit key ---
  uint32_t T = 0;
  int K_rem = KSEL;
  #pragma unroll
  for (int pass = 0; pass < 2; ++pass) {
    const int shift = 8 - pass * 8;
    hist[0][t] = 0; hist[1][t] = 0; hist[2][t] = 0; hist[3][t] = 0;
    __syncthreads();
    #pragma unroll
    for (int j = 0; j < 16; ++j) {
      bool ok = (pass == 0) || ((key[j] >> 8) == T);
      if (ok) atomicAdd(&hist[wid][(key[j] >> shift) & 255], 1);
    }
    __syncthreads();
    if (wid == 0) {
      const int b0 = lane << 2;
      int h0 = hist[0][b0]     + hist[1][b0]     + hist[2][b0]     + hist[3][b0];
      int h1 = hist[0][b0 + 1] + hist[1][b0 + 1] + hist[2][b0 + 1] + hist[3][b0 + 1];
      int h2 = hist[0][b0 + 2] + hist[1][b0 + 2] + hist[2][b0 + 2] + hist[3][b0 + 2];
      int h3 = hist[0][b0 + 3] + hist[1][b0 + 3] + hist[2][b0 + 3] + hist[3][b0 + 3];
      int loc = h0 + h1 + h2 + h3;
      int s = loc;
      #pragma unroll
      for (int off = 1; off < 64; off <<= 1) {
        int o = __shfl_down(s, off);
        if (lane + off < 64) s += o;
      }
      const int tail = s - loc;
      int s3 = tail + h3;
      int s2 = s3 + h2;
      int s1 = s2 + h1;
      int s0 = s1 + h0;
      int ge[4] = {s0, s1, s2, s3};
      int hh[4] = {h0, h1, h2, h3};
      #pragma unroll
      for (int k = 0; k < 4; ++k) {
        int gt = ge[k] - hh[k];
        if (gt < K_rem && ge[k] >= K_rem) {
          selInfo[0] = b0 + k;
          selInfo[1] = K_rem - gt;
        }
      }
    }
    __syncthreads();
    T = (T << 8) | (uint32_t)selInfo[0];
    K_rem = selInfo[1];
  }
  // invert key map: exact 16th-largest stored value
  const u16 ub = (T & 0x8000) ? (u16)(T ^ 0x8000) : (u16)(~T & 0xFFFF);
  const float a16 = bf2f(ub);
  const float vhi = a16 + DELTA;
  const float vlo = a16 - DELTA;
  const float inv = invn[row];

  // --- deterministic scan-based compaction: certain-ins & window ---
  int lcC = 0, lcW = 0;
  #pragma unroll
  for (int j = 0; j < 16; ++j) {
    float v = fv[j];
    if (v > vhi) ++lcC;
    else if (v >= vlo) ++lcW;
  }
  int pC = lcC, pW = lcW;
  #pragma unroll
  for (int off = 1; off < 64; off <<= 1) {
    int oC = __shfl_up(pC, off);
    int oW = __shfl_up(pW, off);
    if (lane >= off) { pC += oC; pW += oW; }
  }
  if (lane == 63) { wtotC[wid] = pC; wtotW[wid] = pW; }
  __syncthreads();
  int baseC = pC - lcC, baseW = pW - lcW;
  for (int w2 = 0; w2 < wid; ++w2) { baseC += wtotC[w2]; baseW += wtotW[w2]; }
  const int m  = wtotC[0] + wtotC[1] + wtotC[2] + wtotC[3];       // <= 15
  const int wc = min(wtotW[0] + wtotW[1] + wtotW[2] + wtotW[3], CAP);
  #pragma unroll
  for (int j = 0; j < 16; ++j) {
    float v = fv[j];
    int pos = (j >> 3) * 2048 + t * 8 + (j & 7);   // column index
    if (v > vhi) { cposC[baseC] = pos; cargC[baseC] = v; ++baseC; }
    else if (v >= vlo) { if (baseW < CAP) { wpos[baseW] = pos; ++baseW; } }
  }
  __syncthreads();

  // --- exact fp32 rescore of WINDOW members only (proven R7 path) ---
  for (int ci = wid; ci < wc; ci += 4) {
    int pidx = wpos[ci];
    const f32x4* pr = reinterpret_cast<const f32x4*>(protos + (size_t)pidx * K_DIM);
    float s = 0.f;
    #pragma unroll
    for (int i = 0; i < 8; ++i) {
      f32x4 pv = pr[i * 64 + lane];
      f32x4 xv = lx[i * 64 + lane];
      s = fmaf(pv.x, xv.x, s);
      s = fmaf(pv.y, xv.y, s);
      s = fmaf(pv.z, xv.z, s);
      s = fmaf(pv.w, xv.w, s);
    }
    #pragma unroll
    for (int off = 1; off < 64; off <<= 1) s += __shfl_xor(s, off);
    if (lane == 0) cexact[ci] = s * inv;
  }
  __syncthreads();

  // --- wave 0: pick top-(16-m) of window, merge, softmax over 16 ---
  if (wid == 0) {
    const int w_need = TOPK - m;   // >= 1 since m <= 15
    float v = (lane < wc) ? cexact[lane] : -3.0e38f;
    int pos = (lane < wc) ? wpos[lane] : 0x7fffffff;
    int rank = 0;
    for (int j = 0; j < wc; ++j) {
      float vj = __shfl(v, j);
      int   pj = __shfl(pos, j);
      if (lane < wc && j != lane)
        if (vj > v || (vj == v && pj < pos)) rank++;
    }
    bool sel = (lane < wc) && (rank < w_need);
    unsigned long long bal = __ballot(sel);
    int slot = __popcll(bal & ((1ull << lane) - 1ull));
    if (sel) { spos[m + slot] = pos; sval[m + slot] = v; }
    if (lane < m) { spos[lane] = cposC[lane]; sval[lane] = cargC[lane] * inv; }
    float av = (lane < TOPK) ? sval[lane] : -3.0e38f;
    float vm = av;
    #pragma unroll
    for (int off = 1; off < 16; off <<= 1) vm = fmaxf(vm, __shfl_xor(vm, off));
    float e = (lane < TOPK) ? expf((av - vm) * INV_T) : 0.f;
    float se = e;
    #pragma unroll
    for (int off = 1; off < 16; off <<= 1) se += __shfl_xor(se, off);
    if (lane < TOPK) {
      sposg[(size_t)row * TOPK + lane] = spos[lane];
      svalg[(size_t)row * TOPK + lane] = e / se;
    }
  }
}

// ---- pure-streaming output writer: zeros + 16 scattered values per row ----
__global__ __launch_bounds__(256) void writer_kernel(
    const int* __restrict__ sposg, const float* __restrict__ svalg,
    float* __restrict__ out) {
  const int row = blockIdx.x;
  const int t = threadIdx.x;
  __shared__ int sp[TOPK];
  __shared__ float svv[TOPK];
  if (t < TOPK) {
    sp[t] = sposg[(size_t)row * TOPK + t];
    svv[t] = svalg[(size_t)row * TOPK + t];
  }
  __syncthreads();
  f32x4* orow4w = reinterpret_cast<f32x4*>(out + (size_t)row * N_COLS);
  #pragma unroll
  for (int i = 0; i < 4; ++i) {
    f32x4 o = (f32x4){0.f, 0.f, 0.f, 0.f};
    #pragma unroll
    for (int s = 0; s < TOPK; ++s) {
      int p = sp[s];
      if ((p >> 10) == i && ((p >> 2) & 255) == t) o[p & 3] = svv[s];
    }
    __builtin_nontemporal_store(o, orow4w + i * 256 + t);
  }
}

extern "C" void kernel_launch(void* const* d_in, const int* in_sizes, int n_in,
                              void* d_out, int out_size, void* d_ws, size_t ws_size,
                              hipStream_t stream) {
  const float* x = (const float*)d_in[0];
  const float* protos = (const float*)d_in[1];
  float* out = (float*)d_out;

  char* ws = (char*)d_ws;
  u16* xh = (u16*)ws;                                        // 64 MB
  u16* ph = (u16*)(ws + (size_t)M_ROWS * K_DIM * 2);         // 16 MB (dead after gemm)
  float* invn = (float*)(ws + (size_t)(M_ROWS + N_COLS) * K_DIM * 2); // 64 KB
  // pair buffers alias the ph region — safe: topk runs after gemm completes
  int*   sposg = (int*)(ws + (size_t)M_ROWS * K_DIM * 2);               // 1 MB
  float* svalg = (float*)(ws + (size_t)M_ROWS * K_DIM * 2 + (size_t)M_ROWS * TOPK * 4); // 1 MB

  // bf16 sims live in the first half of d_out; writer overwrites all of
  // d_out with the final fp32 zeros+values AFTER topk has consumed them.
  u16* simsbf = (u16*)d_out;   // 134 MB of the 268 MB output buffer

  prep_x_kernel<<<M_ROWS, 256, 0, stream>>>(x, xh, invn);
  prep_p_kernel<<<N_COLS, 256, 0, stream>>>(protos, ph);

  const int nblk = (N_COLS / BN) * (M_ROWS / BM);   // 32*128 = 4096
  gemm_bf16_kernel<<<nblk, 256, 0, stream>>>(xh, ph, simsbf);

  topk_kernel<<<M_ROWS, 256, 0, stream>>>(x, protos, invn, simsbf, sposg, svalg);
  writer_kernel<<<M_ROWS, 256, 0, stream>>>(sposg, svalg, out);
}

// Round 14
// 511.501 us; speedup vs baseline: 1.2641x; 1.0451x over previous
//
#include <hip/hip_runtime.h>
#include <hip/hip_bf16.h>
#include <stdint.h>

typedef __attribute__((ext_vector_type(8))) short bf16x8;
typedef __attribute__((ext_vector_type(4))) float f32x4;
typedef unsigned short u16;

#define M_ROWS 16384
#define N_COLS 4096
#define K_DIM  2048
#define TOPK   16
#define KSEL   16
#define CAP    48
#define INV_T  5.0f
#define DELTA  0.035f

#define BM 128
#define BN 128
#define BK 64
#define NKT (K_DIM / BK)   // 32

// ---- async global->LDS 16B copy -------------------------------------------
__device__ __forceinline__ void async_cp16(const void* g, void* l) {
  __builtin_amdgcn_global_load_lds((const __attribute__((address_space(1))) uint32_t*)g,
                                   (__attribute__((address_space(3))) uint32_t*)l,
                                   16, 0, 0);
}

__device__ __forceinline__ u16 f2bf(float f) {
  __hip_bfloat16 h = __float2bfloat16(f);   // round-to-nearest-even
  return *reinterpret_cast<u16*>(&h);
}
__device__ __forceinline__ float bf2f(u16 u) {
  return __uint_as_float(((uint32_t)u) << 16);
}
__device__ __forceinline__ uint2 pack4(float4 v) {
  uint2 r;
  r.x = (uint32_t)f2bf(v.x) | ((uint32_t)f2bf(v.y) << 16);
  r.y = (uint32_t)f2bf(v.z) | ((uint32_t)f2bf(v.w) << 16);
  return r;
}

// ---- prep: per-row inv-norm of x + bf16 cast (unnormalized) ---------------
__global__ __launch_bounds__(256) void prep_x_kernel(
    const float* __restrict__ x, u16* __restrict__ xh, float* __restrict__ invn) {
  const int row = blockIdx.x;
  const int t = threadIdx.x;
  const float4* xr = reinterpret_cast<const float4*>(x + (size_t)row * K_DIM);
  float4 v0 = xr[t];
  float4 v1 = xr[256 + t];
  float s = v0.x*v0.x + v0.y*v0.y + v0.z*v0.z + v0.w*v0.w
          + v1.x*v1.x + v1.y*v1.y + v1.z*v1.z + v1.w*v1.w;
  #pragma unroll
  for (int off = 1; off < 64; off <<= 1) s += __shfl_xor(s, off);
  __shared__ float ws4[4];
  if ((t & 63) == 0) ws4[t >> 6] = s;
  __syncthreads();
  if (t == 0) {
    float tot = ws4[0] + ws4[1] + ws4[2] + ws4[3];
    invn[row] = 1.0f / fmaxf(sqrtf(tot), 1e-12f);
  }
  uint2* xo = reinterpret_cast<uint2*>(xh + (size_t)row * K_DIM);
  xo[t] = pack4(v0);
  xo[256 + t] = pack4(v1);
}

// ---- prep: protos fp32 -> bf16 --------------------------------------------
__global__ __launch_bounds__(256) void prep_p_kernel(
    const float* __restrict__ p, u16* __restrict__ ph) {
  const int row = blockIdx.x;
  const int t = threadIdx.x;
  const float4* pr = reinterpret_cast<const float4*>(p + (size_t)row * K_DIM);
  uint2* po = reinterpret_cast<uint2*>(ph + (size_t)row * K_DIM);
  po[t] = pack4(pr[t]);
  po[256 + t] = pack4(pr[256 + t]);
}

// ---- bf16 GEMM 128x128, dbuf LDS, reg-prefetch, counted vmcnt -------------
// K-loop and 2D grid FROZEN from R11 (proven 268us / FETCH 327K). The R13
// XCD swizzle experiment is reverted: it raised FETCH to 557K (+70%) because
// each XCD's resident set needed all 32 B-panels (16MB >> 4MB L2) while
// breaking the row-major dispatch's implicit A-panel sharing.
__global__ __launch_bounds__(256) void gemm_bf16_kernel(
    const u16* __restrict__ A, const u16* __restrict__ B, u16* __restrict__ C) {
  __shared__ __align__(16) u16 sA[2][BM * BK];   // 2 x 16 KB
  __shared__ __align__(16) u16 sB[2][BN * BK];   // 2 x 16 KB
  const int t = threadIdx.x;
  const int lane = t & 63;
  const int wid = t >> 6;
  const int wm = wid >> 1, wn = wid & 1;
  const int tm0 = blockIdx.y * BM;
  const int tn0 = blockIdx.x * BN;
  const int lr = lane & 15;
  const int hi = lane >> 4;

  f32x4 acc[4][4];
  #pragma unroll
  for (int i = 0; i < 4; ++i)
    #pragma unroll
    for (int j = 0; j < 4; ++j)
      acc[i][j] = (f32x4){0.f, 0.f, 0.f, 0.f};

  int srow[4], soff[4];
  #pragma unroll
  for (int i = 0; i < 4; ++i) {
    int c = i * 256 + t;
    int r = c >> 3;
    int ib = (c & 7) << 4;
    srow[i] = r;
    soff[i] = ib ^ ((r & 7) << 4);
  }
  const char* Abase = (const char*)(A + (size_t)tm0 * K_DIM);
  const char* Bbase = (const char*)(B + (size_t)tn0 * K_DIM);

#define STAGE(slot, kt_) do {                                                 \
    const int kb_ = (kt_) * (BK * 2);                                         \
    _Pragma("unroll")                                                         \
    for (int i = 0; i < 4; ++i) {                                             \
      async_cp16(Abase + (size_t)srow[i] * (K_DIM * 2) + kb_ + soff[i],       \
                 (char*)sA[slot] + (i * 256 + t) * 16);                       \
      async_cp16(Bbase + (size_t)srow[i] * (K_DIM * 2) + kb_ + soff[i],       \
                 (char*)sB[slot] + (i * 256 + t) * 16);                       \
    }                                                                         \
  } while (0)

  STAGE(0, 0);
  STAGE(1, 1);

  for (int kt = 0; kt < NKT; ++kt) {
    // head wait: own tile-kt loads landed; tile kt+1's stay in flight
    if (kt + 1 < NKT) asm volatile("s_waitcnt vmcnt(8)" ::: "memory");
    else              asm volatile("s_waitcnt vmcnt(0)" ::: "memory");
    __builtin_amdgcn_sched_barrier(0);
    __builtin_amdgcn_s_barrier();      // all waves: tile kt ready
    asm volatile("" ::: "memory");

    const char* cA = (const char*)sA[kt & 1];
    const char* cB = (const char*)sB[kt & 1];
    bf16x8 af[4][2], bq[4][2];
    #pragma unroll
    for (int f = 0; f < 4; ++f) {
      #pragma unroll
      for (int kk = 0; kk < 2; ++kk) {
        int rowA = wm * 64 + f * 16 + lr;
        int inbA = (kk * 64 + (hi << 4)) ^ ((rowA & 7) << 4);
        af[f][kk] = *reinterpret_cast<const bf16x8*>(cA + rowA * 128 + inbA);
        int rowB = wn * 64 + f * 16 + lr;
        int inbB = (kk * 64 + (hi << 4)) ^ ((rowB & 7) << 4);
        bq[f][kk] = *reinterpret_cast<const bf16x8*>(cB + rowB * 128 + inbB);
      }
    }
    asm volatile("s_waitcnt lgkmcnt(0)" ::: "memory");   // frags in regs
    __builtin_amdgcn_sched_barrier(0);
    if (kt + 2 < NKT) {
      __builtin_amdgcn_s_barrier();    // WAR seal: all waves done reading buf
      asm volatile("" ::: "memory");
      __builtin_amdgcn_sched_barrier(0);
      STAGE(kt & 1, kt + 2);           // overwrite vacated buffer
    }
    __builtin_amdgcn_s_setprio(1);
    #pragma unroll
    for (int kk = 0; kk < 2; ++kk)
      #pragma unroll
      for (int i = 0; i < 4; ++i)
        #pragma unroll
        for (int j = 0; j < 4; ++j)
          acc[i][j] = __builtin_amdgcn_mfma_f32_16x16x32_bf16(
              af[i][kk], bq[j][kk], acc[i][j], 0, 0, 0);
    __builtin_amdgcn_s_setprio(0);
  }
#undef STAGE

  // C write (bf16): col = lane&15, row = (lane>>4)*4 + reg
  #pragma unroll
  for (int i = 0; i < 4; ++i) {
    #pragma unroll
    for (int j = 0; j < 4; ++j) {
      int colg = tn0 + wn * 64 + j * 16 + lr;
      int rowb = tm0 + wm * 64 + i * 16 + (hi << 2);
      #pragma unroll
      for (int r = 0; r < 4; ++r) {
        __builtin_nontemporal_store(f2bf(acc[i][j][r]),
                                    &C[(size_t)(rowb + r) * N_COLS + colg]);
      }
    }
  }
}

// ---- per-row: 2-pass radix (exact 16-bit keys) -> window rescore -> top-16
// Frozen from R11/R13; DELTA = 0.035 (proven R13: absmax unchanged).
__global__ __launch_bounds__(256) void topk_kernel(
    const float* __restrict__ x, const float* __restrict__ protos,
    const float* __restrict__ invn, const u16* __restrict__ sims,
    int* __restrict__ sposg, float* __restrict__ svalg) {
  const int row = blockIdx.x;
  const int t = threadIdx.x;
  const int lane = t & 63;
  const int wid = t >> 6;

  __shared__ __align__(16) f32x4 lx[512];       // x row, 8 KB
  __shared__ int hist[4][257];                  // padded -> distinct banks
  __shared__ int selInfo[2];
  __shared__ int   wtotC[4], wtotW[4];
  __shared__ int   cposC[16];
  __shared__ float cargC[16];
  __shared__ int   wpos[CAP];
  __shared__ float cexact[CAP];
  __shared__ int   spos[TOPK];
  __shared__ float sval[TOPK];

  // load approx sims (bf16, nt) -> floats + exact 16-bit order keys
  const bf16x8* orow8 = reinterpret_cast<const bf16x8*>(sims + (size_t)row * N_COLS);
  float fv[16];
  uint32_t key[16];
  #pragma unroll
  for (int i = 0; i < 2; ++i) {
    bf16x8 v = __builtin_nontemporal_load(orow8 + i * 256 + t);
    #pragma unroll
    for (int c = 0; c < 8; ++c) {
      u16 u = (u16)v[c];
      fv[i * 8 + c] = bf2f(u);
      key[i * 8 + c] = (u & 0x8000) ? (uint32_t)(~u & 0xFFFF)
                                    : (uint32_t)(u | 0x8000);
    }
  }

  // stage x row into LDS (nt, streaming)
  const f32x4* xr = reinterpret_cast<const f32x4*>(x + (size_t)row * K_DIM);
  lx[t] = __builtin_nontemporal_load(xr + t);
  lx[256 + t] = __builtin_nontemporal_load(xr + 256 + t);

  // --- 2-pass radix select: exact KSEL-th largest 16-bit key ---
  uint32_t T = 0;
  int K_rem = KSEL;
  #pragma unroll
  for (int pass = 0; pass < 2; ++pass) {
    const int shift = 8 - pass * 8;
    hist[0][t] = 0; hist[1][t] = 0; hist[2][t] = 0; hist[3][t] = 0;
    __syncthreads();
    #pragma unroll
    for (int j = 0; j < 16; ++j) {
      bool ok = (pass == 0) || ((key[j] >> 8) == T);
      if (ok) atomicAdd(&hist[wid][(key[j] >> shift) & 255], 1);
    }
    __syncthreads();
    if (wid == 0) {
      const int b0 = lane << 2;
      int h0 = hist[0][b0]     + hist[1][b0]     + hist[2][b0]     + hist[3][b0];
      int h1 = hist[0][b0 + 1] + hist[1][b0 + 1] + hist[2][b0 + 1] + hist[3][b0 + 1];
      int h2 = hist[0][b0 + 2] + hist[1][b0 + 2] + hist[2][b0 + 2] + hist[3][b0 + 2];
      int h3 = hist[0][b0 + 3] + hist[1][b0 + 3] + hist[2][b0 + 3] + hist[3][b0 + 3];
      int loc = h0 + h1 + h2 + h3;
      int s = loc;
      #pragma unroll
      for (int off = 1; off < 64; off <<= 1) {
        int o = __shfl_down(s, off);
        if (lane + off < 64) s += o;
      }
      const int tail = s - loc;
      int s3 = tail + h3;
      int s2 = s3 + h2;
      int s1 = s2 + h1;
      int s0 = s1 + h0;
      int ge[4] = {s0, s1, s2, s3};
      int hh[4] = {h0, h1, h2, h3};
      #pragma unroll
      for (int k = 0; k < 4; ++k) {
        int gt = ge[k] - hh[k];
        if (gt < K_rem && ge[k] >= K_rem) {
          selInfo[0] = b0 + k;
          selInfo[1] = K_rem - gt;
        }
      }
    }
    __syncthreads();
    T = (T << 8) | (uint32_t)selInfo[0];
    K_rem = selInfo[1];
  }
  // invert key map: exact 16th-largest stored value
  const u16 ub = (T & 0x8000) ? (u16)(T ^ 0x8000) : (u16)(~T & 0xFFFF);
  const float a16 = bf2f(ub);
  const float vhi = a16 + DELTA;
  const float vlo = a16 - DELTA;
  const float inv = invn[row];

  // --- deterministic scan-based compaction: certain-ins & window ---
  int lcC = 0, lcW = 0;
  #pragma unroll
  for (int j = 0; j < 16; ++j) {
    float v = fv[j];
    if (v > vhi) ++lcC;
    else if (v >= vlo) ++lcW;
  }
  int pC = lcC, pW = lcW;
  #pragma unroll
  for (int off = 1; off < 64; off <<= 1) {
    int oC = __shfl_up(pC, off);
    int oW = __shfl_up(pW, off);
    if (lane >= off) { pC += oC; pW += oW; }
  }
  if (lane == 63) { wtotC[wid] = pC; wtotW[wid] = pW; }
  __syncthreads();
  int baseC = pC - lcC, baseW = pW - lcW;
  for (int w2 = 0; w2 < wid; ++w2) { baseC += wtotC[w2]; baseW += wtotW[w2]; }
  const int m  = wtotC[0] + wtotC[1] + wtotC[2] + wtotC[3];       // <= 15
  const int wc = min(wtotW[0] + wtotW[1] + wtotW[2] + wtotW[3], CAP);
  #pragma unroll
  for (int j = 0; j < 16; ++j) {
    float v = fv[j];
    int pos = (j >> 3) * 2048 + t * 8 + (j & 7);   // column index
    if (v > vhi) { cposC[baseC] = pos; cargC[baseC] = v; ++baseC; }
    else if (v >= vlo) { if (baseW < CAP) { wpos[baseW] = pos; ++baseW; } }
  }
  __syncthreads();

  // --- exact fp32 rescore of WINDOW members only (proven R7 path) ---
  for (int ci = wid; ci < wc; ci += 4) {
    int pidx = wpos[ci];
    const f32x4* pr = reinterpret_cast<const f32x4*>(protos + (size_t)pidx * K_DIM);
    float s = 0.f;
    #pragma unroll
    for (int i = 0; i < 8; ++i) {
      f32x4 pv = pr[i * 64 + lane];
      f32x4 xv = lx[i * 64 + lane];
      s = fmaf(pv.x, xv.x, s);
      s = fmaf(pv.y, xv.y, s);
      s = fmaf(pv.z, xv.z, s);
      s = fmaf(pv.w, xv.w, s);
    }
    #pragma unroll
    for (int off = 1; off < 64; off <<= 1) s += __shfl_xor(s, off);
    if (lane == 0) cexact[ci] = s * inv;
  }
  __syncthreads();

  // --- wave 0: pick top-(16-m) of window, merge, softmax over 16 ---
  if (wid == 0) {
    const int w_need = TOPK - m;   // >= 1 since m <= 15
    float v = (lane < wc) ? cexact[lane] : -3.0e38f;
    int pos = (lane < wc) ? wpos[lane] : 0x7fffffff;
    int rank = 0;
    for (int j = 0; j < wc; ++j) {
      float vj = __shfl(v, j);
      int   pj = __shfl(pos, j);
      if (lane < wc && j != lane)
        if (vj > v || (vj == v && pj < pos)) rank++;
    }
    bool sel = (lane < wc) && (rank < w_need);
    unsigned long long bal = __ballot(sel);
    int slot = __popcll(bal & ((1ull << lane) - 1ull));
    if (sel) { spos[m + slot] = pos; sval[m + slot] = v; }
    if (lane < m) { spos[lane] = cposC[lane]; sval[lane] = cargC[lane] * inv; }
    float av = (lane < TOPK) ? sval[lane] : -3.0e38f;
    float vm = av;
    #pragma unroll
    for (int off = 1; off < 16; off <<= 1) vm = fmaxf(vm, __shfl_xor(vm, off));
    float e = (lane < TOPK) ? expf((av - vm) * INV_T) : 0.f;
    float se = e;
    #pragma unroll
    for (int off = 1; off < 16; off <<= 1) se += __shfl_xor(se, off);
    if (lane < TOPK) {
      sposg[(size_t)row * TOPK + lane] = spos[lane];
      svalg[(size_t)row * TOPK + lane] = e / se;
    }
  }
}

// ---- pure-streaming output writer: zeros + 16 scattered values per row ----
__global__ __launch_bounds__(256) void writer_kernel(
    const int* __restrict__ sposg, const float* __restrict__ svalg,
    float* __restrict__ out) {
  const int row = blockIdx.x;
  const int t = threadIdx.x;
  __shared__ int sp[TOPK];
  __shared__ float svv[TOPK];
  if (t < TOPK) {
    sp[t] = sposg[(size_t)row * TOPK + t];
    svv[t] = svalg[(size_t)row * TOPK + t];
  }
  __syncthreads();
  f32x4* orow4w = reinterpret_cast<f32x4*>(out + (size_t)row * N_COLS);
  #pragma unroll
  for (int i = 0; i < 4; ++i) {
    f32x4 o = (f32x4){0.f, 0.f, 0.f, 0.f};
    #pragma unroll
    for (int s = 0; s < TOPK; ++s) {
      int p = sp[s];
      if ((p >> 10) == i && ((p >> 2) & 255) == t) o[p & 3] = svv[s];
    }
    __builtin_nontemporal_store(o, orow4w + i * 256 + t);
  }
}

extern "C" void kernel_launch(void* const* d_in, const int* in_sizes, int n_in,
                              void* d_out, int out_size, void* d_ws, size_t ws_size,
                              hipStream_t stream) {
  const float* x = (const float*)d_in[0];
  const float* protos = (const float*)d_in[1];
  float* out = (float*)d_out;

  char* ws = (char*)d_ws;
  u16* xh = (u16*)ws;                                        // 64 MB
  u16* ph = (u16*)(ws + (size_t)M_ROWS * K_DIM * 2);         // 16 MB (dead after gemm)
  float* invn = (float*)(ws + (size_t)(M_ROWS + N_COLS) * K_DIM * 2); // 64 KB
  // pair buffers alias the ph region — safe: topk runs after gemm completes
  int*   sposg = (int*)(ws + (size_t)M_ROWS * K_DIM * 2);               // 1 MB
  float* svalg = (float*)(ws + (size_t)M_ROWS * K_DIM * 2 + (size_t)M_ROWS * TOPK * 4); // 1 MB

  // bf16 sims live in the first half of d_out; writer overwrites all of
  // d_out with the final fp32 zeros+values AFTER topk has consumed them.
  u16* simsbf = (u16*)d_out;   // 134 MB of the 268 MB output buffer

  prep_x_kernel<<<M_ROWS, 256, 0, stream>>>(x, xh, invn);
  prep_p_kernel<<<N_COLS, 256, 0, stream>>>(protos, ph);

  dim3 gg(N_COLS / BN, M_ROWS / BM);   // (32, 128)
  gemm_bf16_kernel<<<gg, 256, 0, stream>>>(xh, ph, simsbf);

  topk_kernel<<<M_ROWS, 256, 0, stream>>>(x, protos, invn, simsbf, sposg, svalg);
  writer_kernel<<<M_ROWS, 256, 0, stream>>>(sposg, svalg, out);
}

// Round 16
// 494.729 us; speedup vs baseline: 1.3070x; 1.0339x over previous
//
#include <hip/hip_runtime.h>
#include <hip/hip_bf16.h>
#include <stdint.h>

typedef __attribute__((ext_vector_type(8))) short bf16x8;
typedef __attribute__((ext_vector_type(4))) float f32x4;
typedef __attribute__((ext_vector_type(4))) unsigned int u32x4;
typedef unsigned short u16;

#define M_ROWS 16384
#define N_COLS 4096
#define K_DIM  2048
#define TOPK   16
#define KSEL   16
#define CAP    48
#define INV_T  5.0f
#define DELTA  0.035f

#define BM 128
#define BN 128
#define BK 64
#define NKT (K_DIM / BK)   // 32

// ---- async global->LDS 16B copy -------------------------------------------
__device__ __forceinline__ void async_cp16(const void* g, void* l) {
  __builtin_amdgcn_global_load_lds((const __attribute__((address_space(1))) uint32_t*)g,
                                   (__attribute__((address_space(3))) uint32_t*)l,
                                   16, 0, 0);
}

__device__ __forceinline__ u16 f2bf(float f) {
  __hip_bfloat16 h = __float2bfloat16(f);   // round-to-nearest-even
  return *reinterpret_cast<u16*>(&h);
}
__device__ __forceinline__ float bf2f(u16 u) {
  return __uint_as_float(((uint32_t)u) << 16);
}
__device__ __forceinline__ uint2 pack4(float4 v) {
  uint2 r;
  r.x = (uint32_t)f2bf(v.x) | ((uint32_t)f2bf(v.y) << 16);
  r.y = (uint32_t)f2bf(v.z) | ((uint32_t)f2bf(v.w) << 16);
  return r;
}

// ---- prep: per-row inv-norm of x + bf16 cast (unnormalized) ---------------
__global__ __launch_bounds__(256) void prep_x_kernel(
    const float* __restrict__ x, u16* __restrict__ xh, float* __restrict__ invn) {
  const int row = blockIdx.x;
  const int t = threadIdx.x;
  const float4* xr = reinterpret_cast<const float4*>(x + (size_t)row * K_DIM);
  float4 v0 = xr[t];
  float4 v1 = xr[256 + t];
  float s = v0.x*v0.x + v0.y*v0.y + v0.z*v0.z + v0.w*v0.w
          + v1.x*v1.x + v1.y*v1.y + v1.z*v1.z + v1.w*v1.w;
  #pragma unroll
  for (int off = 1; off < 64; off <<= 1) s += __shfl_xor(s, off);
  __shared__ float ws4[4];
  if ((t & 63) == 0) ws4[t >> 6] = s;
  __syncthreads();
  if (t == 0) {
    float tot = ws4[0] + ws4[1] + ws4[2] + ws4[3];
    invn[row] = 1.0f / fmaxf(sqrtf(tot), 1e-12f);
  }
  uint2* xo = reinterpret_cast<uint2*>(xh + (size_t)row * K_DIM);
  xo[t] = pack4(v0);
  xo[256 + t] = pack4(v1);
}

// ---- prep: protos fp32 -> bf16 --------------------------------------------
__global__ __launch_bounds__(256) void prep_p_kernel(
    const float* __restrict__ p, u16* __restrict__ ph) {
  const int row = blockIdx.x;
  const int t = threadIdx.x;
  const float4* pr = reinterpret_cast<const float4*>(p + (size_t)row * K_DIM);
  uint2* po = reinterpret_cast<uint2*>(ph + (size_t)row * K_DIM);
  po[t] = pack4(pr[t]);
  po[256 + t] = pack4(pr[256 + t]);
}

// ---- bf16 GEMM 128x128, dbuf LDS, reg-prefetch, counted vmcnt -------------
// K-loop and grid FROZEN from R11/R14 (proven 267us / FETCH 327K). New this
// round: coalesced epilogue — stage the 128x128 bf16 C-tile through LDS
// (reusing the staging space after the final vmcnt(0) drain), then store as
// full 256B row segments. Same values, same destinations; store path only.
__global__ __launch_bounds__(256) void gemm_bf16_kernel(
    const u16* __restrict__ A, const u16* __restrict__ B, u16* __restrict__ C) {
  __shared__ __align__(16) u16 smem[2 * BM * BK + 2 * BN * BK];  // 64 KB
  u16 (*sA)[BM * BK] = reinterpret_cast<u16(*)[BM * BK]>(smem);
  u16 (*sB)[BN * BK] = reinterpret_cast<u16(*)[BN * BK]>(smem + 2 * BM * BK);
  const int t = threadIdx.x;
  const int lane = t & 63;
  const int wid = t >> 6;
  const int wm = wid >> 1, wn = wid & 1;
  const int tm0 = blockIdx.y * BM;
  const int tn0 = blockIdx.x * BN;
  const int lr = lane & 15;
  const int hi = lane >> 4;

  f32x4 acc[4][4];
  #pragma unroll
  for (int i = 0; i < 4; ++i)
    #pragma unroll
    for (int j = 0; j < 4; ++j)
      acc[i][j] = (f32x4){0.f, 0.f, 0.f, 0.f};

  int srow[4], soff[4];
  #pragma unroll
  for (int i = 0; i < 4; ++i) {
    int c = i * 256 + t;
    int r = c >> 3;
    int ib = (c & 7) << 4;
    srow[i] = r;
    soff[i] = ib ^ ((r & 7) << 4);
  }
  const char* Abase = (const char*)(A + (size_t)tm0 * K_DIM);
  const char* Bbase = (const char*)(B + (size_t)tn0 * K_DIM);

#define STAGE(slot, kt_) do {                                                 \
    const int kb_ = (kt_) * (BK * 2);                                         \
    _Pragma("unroll")                                                         \
    for (int i = 0; i < 4; ++i) {                                             \
      async_cp16(Abase + (size_t)srow[i] * (K_DIM * 2) + kb_ + soff[i],       \
                 (char*)sA[slot] + (i * 256 + t) * 16);                       \
      async_cp16(Bbase + (size_t)srow[i] * (K_DIM * 2) + kb_ + soff[i],       \
                 (char*)sB[slot] + (i * 256 + t) * 16);                       \
    }                                                                         \
  } while (0)

  STAGE(0, 0);
  STAGE(1, 1);

  for (int kt = 0; kt < NKT; ++kt) {
    // head wait: own tile-kt loads landed; tile kt+1's stay in flight
    if (kt + 1 < NKT) asm volatile("s_waitcnt vmcnt(8)" ::: "memory");
    else              asm volatile("s_waitcnt vmcnt(0)" ::: "memory");
    __builtin_amdgcn_sched_barrier(0);
    __builtin_amdgcn_s_barrier();      // all waves: tile kt ready
    asm volatile("" ::: "memory");

    const char* cA = (const char*)sA[kt & 1];
    const char* cB = (const char*)sB[kt & 1];
    bf16x8 af[4][2], bq[4][2];
    #pragma unroll
    for (int f = 0; f < 4; ++f) {
      #pragma unroll
      for (int kk = 0; kk < 2; ++kk) {
        int rowA = wm * 64 + f * 16 + lr;
        int inbA = (kk * 64 + (hi << 4)) ^ ((rowA & 7) << 4);
        af[f][kk] = *reinterpret_cast<const bf16x8*>(cA + rowA * 128 + inbA);
        int rowB = wn * 64 + f * 16 + lr;
        int inbB = (kk * 64 + (hi << 4)) ^ ((rowB & 7) << 4);
        bq[f][kk] = *reinterpret_cast<const bf16x8*>(cB + rowB * 128 + inbB);
      }
    }
    asm volatile("s_waitcnt lgkmcnt(0)" ::: "memory");   // frags in regs
    __builtin_amdgcn_sched_barrier(0);
    if (kt + 2 < NKT) {
      __builtin_amdgcn_s_barrier();    // WAR seal: all waves done reading buf
      asm volatile("" ::: "memory");
      __builtin_amdgcn_sched_barrier(0);
      STAGE(kt & 1, kt + 2);           // overwrite vacated buffer
    }
    __builtin_amdgcn_s_setprio(1);
    #pragma unroll
    for (int kk = 0; kk < 2; ++kk)
      #pragma unroll
      for (int i = 0; i < 4; ++i)
        #pragma unroll
        for (int j = 0; j < 4; ++j)
          acc[i][j] = __builtin_amdgcn_mfma_f32_16x16x32_bf16(
              af[i][kk], bq[j][kk], acc[i][j], 0, 0, 0);
    __builtin_amdgcn_s_setprio(0);
  }
#undef STAGE

  // ---- coalesced bf16 epilogue via LDS staging ----
  // (final K-iter used vmcnt(0): no global_load_lds outstanding)
  __syncthreads();                     // all waves done with K-loop LDS reads
  u16* ct = smem;                      // 128 x 136 u16 tile (34816 B < 64 KB)
  #pragma unroll
  for (int i = 0; i < 4; ++i) {
    #pragma unroll
    for (int j = 0; j < 4; ++j) {
      int coll = wn * 64 + j * 16 + lr;
      int rowl = wm * 64 + i * 16 + (hi << 2);
      #pragma unroll
      for (int r = 0; r < 4; ++r)
        ct[(rowl + r) * 136 + coll] = f2bf(acc[i][j][r]);
    }
  }
  __syncthreads();
  const size_t cbase = (size_t)tm0 * N_COLS + tn0;
  #pragma unroll
  for (int k = 0; k < 8; ++k) {
    int c = k * 256 + t;               // 2048 chunks of 16B
    int row = c >> 4;
    int colch = c & 15;
    u32x4 v = *reinterpret_cast<const u32x4*>(ct + row * 136 + colch * 8);
    __builtin_nontemporal_store(
        v, reinterpret_cast<u32x4*>(C + cbase + (size_t)row * N_COLS + colch * 8));
  }
}

// ---- per-row: 2-pass radix (exact 16-bit keys) -> window rescore -> top-16
// Frozen from R11/R13; DELTA = 0.035 (proven R13: absmax unchanged).
__global__ __launch_bounds__(256) void topk_kernel(
    const float* __restrict__ x, const float* __restrict__ protos,
    const float* __restrict__ invn, const u16* __restrict__ sims,
    int* __restrict__ sposg, float* __restrict__ svalg) {
  const int row = blockIdx.x;
  const int t = threadIdx.x;
  const int lane = t & 63;
  const int wid = t >> 6;

  __shared__ __align__(16) f32x4 lx[512];       // x row, 8 KB
  __shared__ int hist[4][257];                  // padded -> distinct banks
  __shared__ int selInfo[2];
  __shared__ int   wtotC[4], wtotW[4];
  __shared__ int   cposC[16];
  __shared__ float cargC[16];
  __shared__ int   wpos[CAP];
  __shared__ float cexact[CAP];
  __shared__ int   spos[TOPK];
  __shared__ float sval[TOPK];

  // load approx sims (bf16, nt) -> floats + exact 16-bit order keys
  const bf16x8* orow8 = reinterpret_cast<const bf16x8*>(sims + (size_t)row * N_COLS);
  float fv[16];
  uint32_t key[16];
  #pragma unroll
  for (int i = 0; i < 2; ++i) {
    bf16x8 v = __builtin_nontemporal_load(orow8 + i * 256 + t);
    #pragma unroll
    for (int c = 0; c < 8; ++c) {
      u16 u = (u16)v[c];
      fv[i * 8 + c] = bf2f(u);
      key[i * 8 + c] = (u & 0x8000) ? (uint32_t)(~u & 0xFFFF)
                                    : (uint32_t)(u | 0x8000);
    }
  }

  // stage x row into LDS (nt, streaming)
  const f32x4* xr = reinterpret_cast<const f32x4*>(x + (size_t)row * K_DIM);
  lx[t] = __builtin_nontemporal_load(xr + t);
  lx[256 + t] = __builtin_nontemporal_load(xr + 256 + t);

  // --- 2-pass radix select: exact KSEL-th largest 16-bit key ---
  uint32_t T = 0;
  int K_rem = KSEL;
  #pragma unroll
  for (int pass = 0; pass < 2; ++pass) {
    const int shift = 8 - pass * 8;
    hist[0][t] = 0; hist[1][t] = 0; hist[2][t] = 0; hist[3][t] = 0;
    __syncthreads();
    #pragma unroll
    for (int j = 0; j < 16; ++j) {
      bool ok = (pass == 0) || ((key[j] >> 8) == T);
      if (ok) atomicAdd(&hist[wid][(key[j] >> shift) & 255], 1);
    }
    __syncthreads();
    if (wid == 0) {
      const int b0 = lane << 2;
      int h0 = hist[0][b0]     + hist[1][b0]     + hist[2][b0]     + hist[3][b0];
      int h1 = hist[0][b0 + 1] + hist[1][b0 + 1] + hist[2][b0 + 1] + hist[3][b0 + 1];
      int h2 = hist[0][b0 + 2] + hist[1][b0 + 2] + hist[2][b0 + 2] + hist[3][b0 + 2];
      int h3 = hist[0][b0 + 3] + hist[1][b0 + 3] + hist[2][b0 + 3] + hist[3][b0 + 3];
      int loc = h0 + h1 + h2 + h3;
      int s = loc;
      #pragma unroll
      for (int off = 1; off < 64; off <<= 1) {
        int o = __shfl_down(s, off);
        if (lane + off < 64) s += o;
      }
      const int tail = s - loc;
      int s3 = tail + h3;
      int s2 = s3 + h2;
      int s1 = s2 + h1;
      int s0 = s1 + h0;
      int ge[4] = {s0, s1, s2, s3};
      int hh[4] = {h0, h1, h2, h3};
      #pragma unroll
      for (int k = 0; k < 4; ++k) {
        int gt = ge[k] - hh[k];
        if (gt < K_rem && ge[k] >= K_rem) {
          selInfo[0] = b0 + k;
          selInfo[1] = K_rem - gt;
        }
      }
    }
    __syncthreads();
    T = (T << 8) | (uint32_t)selInfo[0];
    K_rem = selInfo[1];
  }
  // invert key map: exact 16th-largest stored value
  const u16 ub = (T & 0x8000) ? (u16)(T ^ 0x8000) : (u16)(~T & 0xFFFF);
  const float a16 = bf2f(ub);
  const float vhi = a16 + DELTA;
  const float vlo = a16 - DELTA;
  const float inv = invn[row];

  // --- deterministic scan-based compaction: certain-ins & window ---
  int lcC = 0, lcW = 0;
  #pragma unroll
  for (int j = 0; j < 16; ++j) {
    float v = fv[j];
    if (v > vhi) ++lcC;
    else if (v >= vlo) ++lcW;
  }
  int pC = lcC, pW = lcW;
  #pragma unroll
  for (int off = 1; off < 64; off <<= 1) {
    int oC = __shfl_up(pC, off);
    int oW = __shfl_up(pW, off);
    if (lane >= off) { pC += oC; pW += oW; }
  }
  if (lane == 63) { wtotC[wid] = pC; wtotW[wid] = pW; }
  __syncthreads();
  int baseC = pC - lcC, baseW = pW - lcW;
  for (int w2 = 0; w2 < wid; ++w2) { baseC += wtotC[w2]; baseW += wtotW[w2]; }
  const int m  = wtotC[0] + wtotC[1] + wtotC[2] + wtotC[3];       // <= 15
  const int wc = min(wtotW[0] + wtotW[1] + wtotW[2] + wtotW[3], CAP);
  #pragma unroll
  for (int j = 0; j < 16; ++j) {
    float v = fv[j];
    int pos = (j >> 3) * 2048 + t * 8 + (j & 7);   // column index
    if (v > vhi) { cposC[baseC] = pos; cargC[baseC] = v; ++baseC; }
    else if (v >= vlo) { if (baseW < CAP) { wpos[baseW] = pos; ++baseW; } }
  }
  __syncthreads();

  // --- exact fp32 rescore of WINDOW members only (proven R7 path) ---
  for (int ci = wid; ci < wc; ci += 4) {
    int pidx = wpos[ci];
    const f32x4* pr = reinterpret_cast<const f32x4*>(protos + (size_t)pidx * K_DIM);
    float s = 0.f;
    #pragma unroll
    for (int i = 0; i < 8; ++i) {
      f32x4 pv = pr[i * 64 + lane];
      f32x4 xv = lx[i * 64 + lane];
      s = fmaf(pv.x, xv.x, s);
      s = fmaf(pv.y, xv.y, s);
      s = fmaf(pv.z, xv.z, s);
      s = fmaf(pv.w, xv.w, s);
    }
    #pragma unroll
    for (int off = 1; off < 64; off <<= 1) s += __shfl_xor(s, off);
    if (lane == 0) cexact[ci] = s * inv;
  }
  __syncthreads();

  // --- wave 0: pick top-(16-m) of window, merge, softmax over 16 ---
  if (wid == 0) {
    const int w_need = TOPK - m;   // >= 1 since m <= 15
    float v = (lane < wc) ? cexact[lane] : -3.0e38f;
    int pos = (lane < wc) ? wpos[lane] : 0x7fffffff;
    int rank = 0;
    for (int j = 0; j < wc; ++j) {
      float vj = __shfl(v, j);
      int   pj = __shfl(pos, j);
      if (lane < wc && j != lane)
        if (vj > v || (vj == v && pj < pos)) rank++;
    }
    bool sel = (lane < wc) && (rank < w_need);
    unsigned long long bal = __ballot(sel);
    int slot = __popcll(bal & ((1ull << lane) - 1ull));
    if (sel) { spos[m + slot] = pos; sval[m + slot] = v; }
    if (lane < m) { spos[lane] = cposC[lane]; sval[lane] = cargC[lane] * inv; }
    float av = (lane < TOPK) ? sval[lane] : -3.0e38f;
    float vm = av;
    #pragma unroll
    for (int off = 1; off < 16; off <<= 1) vm = fmaxf(vm, __shfl_xor(vm, off));
    float e = (lane < TOPK) ? expf((av - vm) * INV_T) : 0.f;
    float se = e;
    #pragma unroll
    for (int off = 1; off < 16; off <<= 1) se += __shfl_xor(se, off);
    if (lane < TOPK) {
      sposg[(size_t)row * TOPK + lane] = spos[lane];
      svalg[(size_t)row * TOPK + lane] = e / se;
    }
  }
}

// ---- pure-streaming output writer: zeros + 16 scattered values per row ----
__global__ __launch_bounds__(256) void writer_kernel(
    const int* __restrict__ sposg, const float* __restrict__ svalg,
    float* __restrict__ out) {
  const int row = blockIdx.x;
  const int t = threadIdx.x;
  __shared__ int sp[TOPK];
  __shared__ float svv[TOPK];
  if (t < TOPK) {
    sp[t] = sposg[(size_t)row * TOPK + t];
    svv[t] = svalg[(size_t)row * TOPK + t];
  }
  __syncthreads();
  f32x4* orow4w = reinterpret_cast<f32x4*>(out + (size_t)row * N_COLS);
  #pragma unroll
  for (int i = 0; i < 4; ++i) {
    f32x4 o = (f32x4){0.f, 0.f, 0.f, 0.f};
    #pragma unroll
    for (int s = 0; s < TOPK; ++s) {
      int p = sp[s];
      if ((p >> 10) == i && ((p >> 2) & 255) == t) o[p & 3] = svv[s];
    }
    __builtin_nontemporal_store(o, orow4w + i * 256 + t);
  }
}

extern "C" void kernel_launch(void* const* d_in, const int* in_sizes, int n_in,
                              void* d_out, int out_size, void* d_ws, size_t ws_size,
                              hipStream_t stream) {
  const float* x = (const float*)d_in[0];
  const float* protos = (const float*)d_in[1];
  float* out = (float*)d_out;

  char* ws = (char*)d_ws;
  u16* xh = (u16*)ws;                                        // 64 MB
  u16* ph = (u16*)(ws + (size_t)M_ROWS * K_DIM * 2);         // 16 MB (dead after gemm)
  float* invn = (float*)(ws + (size_t)(M_ROWS + N_COLS) * K_DIM * 2); // 64 KB
  // pair buffers alias the ph region — safe: topk runs after gemm completes
  int*   sposg = (int*)(ws + (size_t)M_ROWS * K_DIM * 2);               // 1 MB
  float* svalg = (float*)(ws + (size_t)M_ROWS * K_DIM * 2 + (size_t)M_ROWS * TOPK * 4); // 1 MB

  // bf16 sims live in the first half of d_out; writer overwrites all of
  // d_out with the final fp32 zeros+values AFTER topk has consumed them.
  u16* simsbf = (u16*)d_out;   // 134 MB of the 268 MB output buffer

  prep_x_kernel<<<M_ROWS, 256, 0, stream>>>(x, xh, invn);
  prep_p_kernel<<<N_COLS, 256, 0, stream>>>(protos, ph);

  dim3 gg(N_COLS / BN, M_ROWS / BM);   // (32, 128)
  gemm_bf16_kernel<<<gg, 256, 0, stream>>>(xh, ph, simsbf);

  topk_kernel<<<M_ROWS, 256, 0, stream>>>(x, protos, invn, simsbf, sposg, svalg);
  writer_kernel<<<M_ROWS, 256, 0, stream>>>(sposg, svalg, out);
}

// Round 17
// 486.654 us; speedup vs baseline: 1.3287x; 1.0166x over previous
//
#include <hip/hip_runtime.h>
#include <hip/hip_bf16.h>
#include <stdint.h>

typedef __attribute__((ext_vector_type(8))) short bf16x8;
typedef __attribute__((ext_vector_type(4))) float f32x4;
typedef __attribute__((ext_vector_type(4))) unsigned int u32x4;
typedef unsigned short u16;

#define M_ROWS 16384
#define N_COLS 4096
#define K_DIM  2048
#define TOPK   16
#define KSEL   16
#define CAP    48
#define INV_T  5.0f
#define DELTA  0.028f

#define BM 128
#define BN 128
#define BK 64
#define NKT (K_DIM / BK)   // 32

// ---- async global->LDS 16B copy -------------------------------------------
__device__ __forceinline__ void async_cp16(const void* g, void* l) {
  __builtin_amdgcn_global_load_lds((const __attribute__((address_space(1))) uint32_t*)g,
                                   (__attribute__((address_space(3))) uint32_t*)l,
                                   16, 0, 0);
}

__device__ __forceinline__ u16 f2bf(float f) {
  __hip_bfloat16 h = __float2bfloat16(f);   // round-to-nearest-even
  return *reinterpret_cast<u16*>(&h);
}
__device__ __forceinline__ float bf2f(u16 u) {
  return __uint_as_float(((uint32_t)u) << 16);
}
__device__ __forceinline__ uint2 pack4(float4 v) {
  uint2 r;
  r.x = (uint32_t)f2bf(v.x) | ((uint32_t)f2bf(v.y) << 16);
  r.y = (uint32_t)f2bf(v.z) | ((uint32_t)f2bf(v.w) << 16);
  return r;
}

// ---- fused prep: blocks [0,M) = x rows (norm + cast); [M, M+N) = protos ----
__global__ __launch_bounds__(256) void prep_kernel(
    const float* __restrict__ x, const float* __restrict__ p,
    u16* __restrict__ xh, u16* __restrict__ ph, float* __restrict__ invn) {
  const int b = blockIdx.x;
  const int t = threadIdx.x;
  if (b < M_ROWS) {
    const int row = b;
    const float4* xr = reinterpret_cast<const float4*>(x + (size_t)row * K_DIM);
    float4 v0 = xr[t];
    float4 v1 = xr[256 + t];
    float s = v0.x*v0.x + v0.y*v0.y + v0.z*v0.z + v0.w*v0.w
            + v1.x*v1.x + v1.y*v1.y + v1.z*v1.z + v1.w*v1.w;
    #pragma unroll
    for (int off = 1; off < 64; off <<= 1) s += __shfl_xor(s, off);
    __shared__ float ws4[4];
    if ((t & 63) == 0) ws4[t >> 6] = s;
    __syncthreads();
    if (t == 0) {
      float tot = ws4[0] + ws4[1] + ws4[2] + ws4[3];
      invn[row] = 1.0f / fmaxf(sqrtf(tot), 1e-12f);
    }
    uint2* xo = reinterpret_cast<uint2*>(xh + (size_t)row * K_DIM);
    xo[t] = pack4(v0);
    xo[256 + t] = pack4(v1);
  } else {
    const int row = b - M_ROWS;
    const float4* pr = reinterpret_cast<const float4*>(p + (size_t)row * K_DIM);
    uint2* po = reinterpret_cast<uint2*>(ph + (size_t)row * K_DIM);
    po[t] = pack4(pr[t]);
    po[256 + t] = pack4(pr[256 + t]);
  }
}

// ---- bf16 GEMM 128x128, dbuf LDS, reg-prefetch, counted vmcnt -------------
// K-loop, grid, and coalesced LDS-staged epilogue FROZEN from R16
// (proven 253us / FETCH 327K / WRITE 131K = ideal).
__global__ __launch_bounds__(256) void gemm_bf16_kernel(
    const u16* __restrict__ A, const u16* __restrict__ B, u16* __restrict__ C) {
  __shared__ __align__(16) u16 smem[2 * BM * BK + 2 * BN * BK];  // 64 KB
  u16 (*sA)[BM * BK] = reinterpret_cast<u16(*)[BM * BK]>(smem);
  u16 (*sB)[BN * BK] = reinterpret_cast<u16(*)[BN * BK]>(smem + 2 * BM * BK);
  const int t = threadIdx.x;
  const int lane = t & 63;
  const int wid = t >> 6;
  const int wm = wid >> 1, wn = wid & 1;
  const int tm0 = blockIdx.y * BM;
  const int tn0 = blockIdx.x * BN;
  const int lr = lane & 15;
  const int hi = lane >> 4;

  f32x4 acc[4][4];
  #pragma unroll
  for (int i = 0; i < 4; ++i)
    #pragma unroll
    for (int j = 0; j < 4; ++j)
      acc[i][j] = (f32x4){0.f, 0.f, 0.f, 0.f};

  int srow[4], soff[4];
  #pragma unroll
  for (int i = 0; i < 4; ++i) {
    int c = i * 256 + t;
    int r = c >> 3;
    int ib = (c & 7) << 4;
    srow[i] = r;
    soff[i] = ib ^ ((r & 7) << 4);
  }
  const char* Abase = (const char*)(A + (size_t)tm0 * K_DIM);
  const char* Bbase = (const char*)(B + (size_t)tn0 * K_DIM);

#define STAGE(slot, kt_) do {                                                 \
    const int kb_ = (kt_) * (BK * 2);                                         \
    _Pragma("unroll")                                                         \
    for (int i = 0; i < 4; ++i) {                                             \
      async_cp16(Abase + (size_t)srow[i] * (K_DIM * 2) + kb_ + soff[i],       \
                 (char*)sA[slot] + (i * 256 + t) * 16);                       \
      async_cp16(Bbase + (size_t)srow[i] * (K_DIM * 2) + kb_ + soff[i],       \
                 (char*)sB[slot] + (i * 256 + t) * 16);                       \
    }                                                                         \
  } while (0)

  STAGE(0, 0);
  STAGE(1, 1);

  for (int kt = 0; kt < NKT; ++kt) {
    // head wait: own tile-kt loads landed; tile kt+1's stay in flight
    if (kt + 1 < NKT) asm volatile("s_waitcnt vmcnt(8)" ::: "memory");
    else              asm volatile("s_waitcnt vmcnt(0)" ::: "memory");
    __builtin_amdgcn_sched_barrier(0);
    __builtin_amdgcn_s_barrier();      // all waves: tile kt ready
    asm volatile("" ::: "memory");

    const char* cA = (const char*)sA[kt & 1];
    const char* cB = (const char*)sB[kt & 1];
    bf16x8 af[4][2], bq[4][2];
    #pragma unroll
    for (int f = 0; f < 4; ++f) {
      #pragma unroll
      for (int kk = 0; kk < 2; ++kk) {
        int rowA = wm * 64 + f * 16 + lr;
        int inbA = (kk * 64 + (hi << 4)) ^ ((rowA & 7) << 4);
        af[f][kk] = *reinterpret_cast<const bf16x8*>(cA + rowA * 128 + inbA);
        int rowB = wn * 64 + f * 16 + lr;
        int inbB = (kk * 64 + (hi << 4)) ^ ((rowB & 7) << 4);
        bq[f][kk] = *reinterpret_cast<const bf16x8*>(cB + rowB * 128 + inbB);
      }
    }
    asm volatile("s_waitcnt lgkmcnt(0)" ::: "memory");   // frags in regs
    __builtin_amdgcn_sched_barrier(0);
    if (kt + 2 < NKT) {
      __builtin_amdgcn_s_barrier();    // WAR seal: all waves done reading buf
      asm volatile("" ::: "memory");
      __builtin_amdgcn_sched_barrier(0);
      STAGE(kt & 1, kt + 2);           // overwrite vacated buffer
    }
    __builtin_amdgcn_s_setprio(1);
    #pragma unroll
    for (int kk = 0; kk < 2; ++kk)
      #pragma unroll
      for (int i = 0; i < 4; ++i)
        #pragma unroll
        for (int j = 0; j < 4; ++j)
          acc[i][j] = __builtin_amdgcn_mfma_f32_16x16x32_bf16(
              af[i][kk], bq[j][kk], acc[i][j], 0, 0, 0);
    __builtin_amdgcn_s_setprio(0);
  }
#undef STAGE

  // ---- coalesced bf16 epilogue via LDS staging (R16-proven) ----
  __syncthreads();                     // all waves done with K-loop LDS reads
  u16* ct = smem;                      // 128 x 136 u16 tile (34816 B < 64 KB)
  #pragma unroll
  for (int i = 0; i < 4; ++i) {
    #pragma unroll
    for (int j = 0; j < 4; ++j) {
      int coll = wn * 64 + j * 16 + lr;
      int rowl = wm * 64 + i * 16 + (hi << 2);
      #pragma unroll
      for (int r = 0; r < 4; ++r)
        ct[(rowl + r) * 136 + coll] = f2bf(acc[i][j][r]);
    }
  }
  __syncthreads();
  const size_t cbase = (size_t)tm0 * N_COLS + tn0;
  #pragma unroll
  for (int k = 0; k < 8; ++k) {
    int c = k * 256 + t;               // 2048 chunks of 16B
    int row = c >> 4;
    int colch = c & 15;
    u32x4 v = *reinterpret_cast<const u32x4*>(ct + row * 136 + colch * 8);
    __builtin_nontemporal_store(
        v, reinterpret_cast<u32x4*>(C + cbase + (size_t)row * N_COLS + colch * 8));
  }
}

// ---- per-row: 2-pass radix (exact 16-bit keys) -> window rescore -> top-16
// Frozen from R11/R13/R16; DELTA 0.035 -> 0.028 (margin still >= 1.4x the
// 2x(half-ulp + 5-sigma gemm-err) = 0.020 bound at a16 ~ 3.0).
__global__ __launch_bounds__(256) void topk_kernel(
    const float* __restrict__ x, const float* __restrict__ protos,
    const float* __restrict__ invn, const u16* __restrict__ sims,
    int* __restrict__ sposg, float* __restrict__ svalg) {
  const int row = blockIdx.x;
  const int t = threadIdx.x;
  const int lane = t & 63;
  const int wid = t >> 6;

  __shared__ __align__(16) f32x4 lx[512];       // x row, 8 KB
  __shared__ int hist[4][257];                  // padded -> distinct banks
  __shared__ int selInfo[2];
  __shared__ int   wtotC[4], wtotW[4];
  __shared__ int   cposC[16];
  __shared__ float cargC[16];
  __shared__ int   wpos[CAP];
  __shared__ float cexact[CAP];
  __shared__ int   spos[TOPK];
  __shared__ float sval[TOPK];

  // load approx sims (bf16, nt) -> floats + exact 16-bit order keys
  const bf16x8* orow8 = reinterpret_cast<const bf16x8*>(sims + (size_t)row * N_COLS);
  float fv[16];
  uint32_t key[16];
  #pragma unroll
  for (int i = 0; i < 2; ++i) {
    bf16x8 v = __builtin_nontemporal_load(orow8 + i * 256 + t);
    #pragma unroll
    for (int c = 0; c < 8; ++c) {
      u16 u = (u16)v[c];
      fv[i * 8 + c] = bf2f(u);
      key[i * 8 + c] = (u & 0x8000) ? (uint32_t)(~u & 0xFFFF)
                                    : (uint32_t)(u | 0x8000);
    }
  }

  // stage x row into LDS (nt, streaming)
  const f32x4* xr = reinterpret_cast<const f32x4*>(x + (size_t)row * K_DIM);
  lx[t] = __builtin_nontemporal_load(xr + t);
  lx[256 + t] = __builtin_nontemporal_load(xr + 256 + t);

  // --- 2-pass radix select: exact KSEL-th largest 16-bit key ---
  uint32_t T = 0;
  int K_rem = KSEL;
  #pragma unroll
  for (int pass = 0; pass < 2; ++pass) {
    const int shift = 8 - pass * 8;
    hist[0][t] = 0; hist[1][t] = 0; hist[2][t] = 0; hist[3][t] = 0;
    __syncthreads();
    #pragma unroll
    for (int j = 0; j < 16; ++j) {
      bool ok = (pass == 0) || ((key[j] >> 8) == T);
      if (ok) atomicAdd(&hist[wid][(key[j] >> shift) & 255], 1);
    }
    __syncthreads();
    if (wid == 0) {
      const int b0 = lane << 2;
      int h0 = hist[0][b0]     + hist[1][b0]     + hist[2][b0]     + hist[3][b0];
      int h1 = hist[0][b0 + 1] + hist[1][b0 + 1] + hist[2][b0 + 1] + hist[3][b0 + 1];
      int h2 = hist[0][b0 + 2] + hist[1][b0 + 2] + hist[2][b0 + 2] + hist[3][b0 + 2];
      int h3 = hist[0][b0 + 3] + hist[1][b0 + 3] + hist[2][b0 + 3] + hist[3][b0 + 3];
      int loc = h0 + h1 + h2 + h3;
      int s = loc;
      #pragma unroll
      for (int off = 1; off < 64; off <<= 1) {
        int o = __shfl_down(s, off);
        if (lane + off < 64) s += o;
      }
      const int tail = s - loc;
      int s3 = tail + h3;
      int s2 = s3 + h2;
      int s1 = s2 + h1;
      int s0 = s1 + h0;
      int ge[4] = {s0, s1, s2, s3};
      int hh[4] = {h0, h1, h2, h3};
      #pragma unroll
      for (int k = 0; k < 4; ++k) {
        int gt = ge[k] - hh[k];
        if (gt < K_rem && ge[k] >= K_rem) {
          selInfo[0] = b0 + k;
          selInfo[1] = K_rem - gt;
        }
      }
    }
    __syncthreads();
    T = (T << 8) | (uint32_t)selInfo[0];
    K_rem = selInfo[1];
  }
  // invert key map: exact 16th-largest stored value
  const u16 ub = (T & 0x8000) ? (u16)(T ^ 0x8000) : (u16)(~T & 0xFFFF);
  const float a16 = bf2f(ub);
  const float vhi = a16 + DELTA;
  const float vlo = a16 - DELTA;
  const float inv = invn[row];

  // --- deterministic scan-based compaction: certain-ins & window ---
  int lcC = 0, lcW = 0;
  #pragma unroll
  for (int j = 0; j < 16; ++j) {
    float v = fv[j];
    if (v > vhi) ++lcC;
    else if (v >= vlo) ++lcW;
  }
  int pC = lcC, pW = lcW;
  #pragma unroll
  for (int off = 1; off < 64; off <<= 1) {
    int oC = __shfl_up(pC, off);
    int oW = __shfl_up(pW, off);
    if (lane >= off) { pC += oC; pW += oW; }
  }
  if (lane == 63) { wtotC[wid] = pC; wtotW[wid] = pW; }
  __syncthreads();
  int baseC = pC - lcC, baseW = pW - lcW;
  for (int w2 = 0; w2 < wid; ++w2) { baseC += wtotC[w2]; baseW += wtotW[w2]; }
  const int m  = wtotC[0] + wtotC[1] + wtotC[2] + wtotC[3];       // <= 15
  const int wc = min(wtotW[0] + wtotW[1] + wtotW[2] + wtotW[3], CAP);
  #pragma unroll
  for (int j = 0; j < 16; ++j) {
    float v = fv[j];
    int pos = (j >> 3) * 2048 + t * 8 + (j & 7);   // column index
    if (v > vhi) { cposC[baseC] = pos; cargC[baseC] = v; ++baseC; }
    else if (v >= vlo) { if (baseW < CAP) { wpos[baseW] = pos; ++baseW; } }
  }
  __syncthreads();

  // --- exact fp32 rescore of WINDOW members only (proven R7 path) ---
  for (int ci = wid; ci < wc; ci += 4) {
    int pidx = wpos[ci];
    const f32x4* pr = reinterpret_cast<const f32x4*>(protos + (size_t)pidx * K_DIM);
    float s = 0.f;
    #pragma unroll
    for (int i = 0; i < 8; ++i) {
      f32x4 pv = pr[i * 64 + lane];
      f32x4 xv = lx[i * 64 + lane];
      s = fmaf(pv.x, xv.x, s);
      s = fmaf(pv.y, xv.y, s);
      s = fmaf(pv.z, xv.z, s);
      s = fmaf(pv.w, xv.w, s);
    }
    #pragma unroll
    for (int off = 1; off < 64; off <<= 1) s += __shfl_xor(s, off);
    if (lane == 0) cexact[ci] = s * inv;
  }
  __syncthreads();

  // --- wave 0: pick top-(16-m) of window, merge, softmax over 16 ---
  if (wid == 0) {
    const int w_need = TOPK - m;   // >= 1 since m <= 15
    float v = (lane < wc) ? cexact[lane] : -3.0e38f;
    int pos = (lane < wc) ? wpos[lane] : 0x7fffffff;
    int rank = 0;
    for (int j = 0; j < wc; ++j) {
      float vj = __shfl(v, j);
      int   pj = __shfl(pos, j);
      if (lane < wc && j != lane)
        if (vj > v || (vj == v && pj < pos)) rank++;
    }
    bool sel = (lane < wc) && (rank < w_need);
    unsigned long long bal = __ballot(sel);
    int slot = __popcll(bal & ((1ull << lane) - 1ull));
    if (sel) { spos[m + slot] = pos; sval[m + slot] = v; }
    if (lane < m) { spos[lane] = cposC[lane]; sval[lane] = cargC[lane] * inv; }
    float av = (lane < TOPK) ? sval[lane] : -3.0e38f;
    float vm = av;
    #pragma unroll
    for (int off = 1; off < 16; off <<= 1) vm = fmaxf(vm, __shfl_xor(vm, off));
    float e = (lane < TOPK) ? expf((av - vm) * INV_T) : 0.f;
    float se = e;
    #pragma unroll
    for (int off = 1; off < 16; off <<= 1) se += __shfl_xor(se, off);
    if (lane < TOPK) {
      sposg[(size_t)row * TOPK + lane] = spos[lane];
      svalg[(size_t)row * TOPK + lane] = e / se;
    }
  }
}

// ---- pure-streaming output writer: zeros + 16 scattered values per row ----
__global__ __launch_bounds__(256) void writer_kernel(
    const int* __restrict__ sposg, const float* __restrict__ svalg,
    float* __restrict__ out) {
  const int row = blockIdx.x;
  const int t = threadIdx.x;
  __shared__ int sp[TOPK];
  __shared__ float svv[TOPK];
  if (t < TOPK) {
    sp[t] = sposg[(size_t)row * TOPK + t];
    svv[t] = svalg[(size_t)row * TOPK + t];
  }
  __syncthreads();
  f32x4* orow4w = reinterpret_cast<f32x4*>(out + (size_t)row * N_COLS);
  #pragma unroll
  for (int i = 0; i < 4; ++i) {
    f32x4 o = (f32x4){0.f, 0.f, 0.f, 0.f};
    #pragma unroll
    for (int s = 0; s < TOPK; ++s) {
      int p = sp[s];
      if ((p >> 10) == i && ((p >> 2) & 255) == t) o[p & 3] = svv[s];
    }
    __builtin_nontemporal_store(o, orow4w + i * 256 + t);
  }
}

extern "C" void kernel_launch(void* const* d_in, const int* in_sizes, int n_in,
                              void* d_out, int out_size, void* d_ws, size_t ws_size,
                              hipStream_t stream) {
  const float* x = (const float*)d_in[0];
  const float* protos = (const float*)d_in[1];
  float* out = (float*)d_out;

  char* ws = (char*)d_ws;
  u16* xh = (u16*)ws;                                        // 64 MB
  u16* ph = (u16*)(ws + (size_t)M_ROWS * K_DIM * 2);         // 16 MB (dead after gemm)
  float* invn = (float*)(ws + (size_t)(M_ROWS + N_COLS) * K_DIM * 2); // 64 KB
  // pair buffers alias the ph region — safe: topk runs after gemm completes
  int*   sposg = (int*)(ws + (size_t)M_ROWS * K_DIM * 2);               // 1 MB
  float* svalg = (float*)(ws + (size_t)M_ROWS * K_DIM * 2 + (size_t)M_ROWS * TOPK * 4); // 1 MB

  // bf16 sims live in the first half of d_out; writer overwrites all of
  // d_out with the final fp32 zeros+values AFTER topk has consumed them.
  u16* simsbf = (u16*)d_out;   // 134 MB of the 268 MB output buffer

  prep_kernel<<<M_ROWS + N_COLS, 256, 0, stream>>>(x, protos, xh, ph, invn);

  dim3 gg(N_COLS / BN, M_ROWS / BM);   // (32, 128)
  gemm_bf16_kernel<<<gg, 256, 0, stream>>>(xh, ph, simsbf);

  topk_kernel<<<M_ROWS, 256, 0, stream>>>(x, protos, invn, simsbf, sposg, svalg);
  writer_kernel<<<M_ROWS, 256, 0, stream>>>(sposg, svalg, out);
}